// Round 10
// baseline (205.254 us; speedup 1.0000x reference)
//
#include <hip/hip_runtime.h>

typedef __attribute__((ext_vector_type(8))) short short8v;
typedef __attribute__((ext_vector_type(4))) float f32x4;
typedef __attribute__((ext_vector_type(4))) unsigned short us4;

#define MFMA(a,b,c) __builtin_amdgcn_mfma_f32_16x16x32_bf16(a,b,c,0,0,0)

__device__ __forceinline__ unsigned short f2b(float f){
  unsigned int u = __float_as_uint(f);
  u += 0x7fffu + ((u >> 16) & 1u);   // round-to-nearest-even
  return (unsigned short)(u >> 16);
}
__device__ __forceinline__ float b2f(unsigned short u){
  return __uint_as_float(((unsigned int)u) << 16);
}

__device__ __forceinline__ void gll16(const void* g, void* l){
  __builtin_amdgcn_global_load_lds((const __attribute__((address_space(1))) void*)g,
                                   (__attribute__((address_space(3))) void*)l, 16, 0, 0);
}

__device__ __forceinline__ unsigned int cvtpk(float lo, float hi){
  unsigned int r;
  asm("v_cvt_pk_bf16_f32 %0, %1, %2" : "=v"(r) : "v"(lo), "v"(hi));
  return r;
}
// a=vdst, b=vsrc. pl32: a'=[a0,a1,b0,b1], b'=[a2,a3,b2,b3] (16-lane rows)
__device__ __forceinline__ void pl32swap(unsigned int &a, unsigned int &b){
  asm("v_permlane32_swap_b32 %0, %1" : "+v"(a), "+v"(b));
}
// pl16: a'=[a0,b0,a2,b2], b'=[a1,b1,a3,b3]
__device__ __forceinline__ void pl16swap(unsigned int &a, unsigned int &b){
  asm("v_permlane16_swap_b32 %0, %1" : "+v"(a), "+v"(b));
}

union U8 { unsigned int u[4]; short8v v; };

// ---------------- fused prep: cast x/qkv_w/proj_w to bf16 + count[b] = sum mWin^2 ----------------
__global__ __launch_bounds__(256) void prep_k(
    const float* __restrict__ x, const float* __restrict__ qkv_w,
    const float* __restrict__ proj_w, const float* __restrict__ mWin,
    unsigned short* __restrict__ xb, unsigned short* __restrict__ wqkvb,
    unsigned short* __restrict__ wprojb, float* __restrict__ cnt){
  int blk = blockIdx.x, tid = threadIdx.x;
  const float* src; unsigned short* dst; int base;
  if (blk < 8192){ src = x; dst = xb; base = 0; }
  else if (blk < 11264){ src = qkv_w; dst = wqkvb; base = 8192; }
  else if (blk < 12288){ src = proj_w; dst = wprojb; base = 11264; }
  else {
    int b = blk - 12288;
    float s = 0.f;
    for (int i = tid; i < 2048; i += 256){ float m = mWin[b*2048 + i]; s += m*m; }
    #pragma unroll
    for (int o = 32; o >= 1; o >>= 1) s += __shfl_xor(s, o, 64);
    if ((tid & 63) == 0) atomicAdd(&cnt[b], s);
    return;
  }
  int i = (blk - base)*256 + tid;
  float4 v = reinterpret_cast<const float4*>(src)[i];
  us4 o; o.x = f2b(v.x); o.y = f2b(v.y); o.z = f2b(v.z); o.w = f2b(v.w);
  reinterpret_cast<us4*>(dst)[i] = o;
}

// ---------------- qkv GEMM: xb[8192x1024] @ wb[3072x1024]^T -> masked/scaled q,k,v bf16 ----------------
// q,k layout: [B*H][N][hd] = [64][2048][64]; v layout TRANSPOSED: [B*H][hd][N] = [64][64][2048]
// q additionally scaled by log2(e) so attention can use exp2 directly.
__global__ __launch_bounds__(256,2) void qkv_gemm(
    const unsigned short* __restrict__ xb,
    const unsigned short* __restrict__ wb,
    const float* __restrict__ mWin,
    unsigned short* __restrict__ qb,
    unsigned short* __restrict__ kb,
    unsigned short* __restrict__ vb)
{
  __shared__ unsigned short As[128*64];
  __shared__ unsigned short Bs[128*64];
  int lin = blockIdx.x;                       // 1536 blocks
  int swz = (lin & 7) * 192 + (lin >> 3);     // XCD swizzle (1536 % 8 == 0)
  int tM = swz & 63, tN = swz >> 6;           // 64 x 24
  int tid = threadIdx.x, lane = tid & 63, wv = tid >> 6;
  int lr = lane & 15, lg = lane >> 4;

  const unsigned short* ga[4]; const unsigned short* gbp[4];
  char* lA[4]; char* lB[4];
  #pragma unroll
  for (int c = 0; c < 4; ++c){
    int o = c*4096 + wv*1024 + lane*16;       // byte offset within 16KB tile
    int row = o >> 7, cole = (o & 127) >> 1;
    ga[c]  = xb + (tM*128 + row)*1024 + cole;
    gbp[c] = wb + (tN*128 + row)*1024 + cole;
    lA[c] = (char*)As + c*4096 + wv*1024;     // wave-uniform LDS base
    lB[c] = (char*)Bs + c*4096 + wv*1024;
  }

  f32x4 acc[4][4];
  #pragma unroll
  for (int i = 0; i < 4; ++i)
    #pragma unroll
    for (int j = 0; j < 4; ++j) acc[i][j] = (f32x4){0.f,0.f,0.f,0.f};

  int wr = (wv >> 1) * 64, wc = (wv & 1) * 64;

  for (int it = 0; it < 16; ++it){
    #pragma unroll
    for (int c = 0; c < 4; ++c){
      gll16(ga[c]  + it*64, lA[c]);
      gll16(gbp[c] + it*64, lB[c]);
    }
    __syncthreads();
    short8v af[4][2], bf[4][2];
    #pragma unroll
    for (int mi = 0; mi < 4; ++mi)
      #pragma unroll
      for (int ks = 0; ks < 2; ++ks)
        af[mi][ks] = *(const short8v*)&As[(wr + mi*16 + lr)*64 + ks*32 + lg*8];
    #pragma unroll
    for (int ni = 0; ni < 4; ++ni)
      #pragma unroll
      for (int ks = 0; ks < 2; ++ks)
        bf[ni][ks] = *(const short8v*)&Bs[(wc + ni*16 + lr)*64 + ks*32 + lg*8];
    #pragma unroll
    for (int mi = 0; mi < 4; ++mi)
      #pragma unroll
      for (int ni = 0; ni < 4; ++ni)
        #pragma unroll
        for (int ks = 0; ks < 2; ++ks)
          acc[mi][ni] = MFMA(af[mi][ks], bf[ni][ks], acc[mi][ni]);
    __syncthreads();
  }

  // epilogue: scatter to q/k/v with mask (+scale*log2e for q); v stored transposed
  int which = tN >> 3;               // 0=q 1=k 2=v (128-col tiles never straddle)
  int c0 = (tN & 7) * 128;
  if (which == 2){
    #pragma unroll
    for (int mi = 0; mi < 4; ++mi){
      int m0 = tM*128 + wr + mi*16 + lg*4;     // m = b*2048 + n, 4 consecutive rows
      int b = m0 >> 11, n0 = m0 & 2047;
      float f0 = mWin[m0], f1 = mWin[m0+1], f2 = mWin[m0+2], f3 = mWin[m0+3];
      #pragma unroll
      for (int ni = 0; ni < 4; ++ni){
        int col = c0 + wc + ni*16 + lr;
        int h = col >> 6, d = col & 63;
        us4 o;
        o.x = f2b(acc[mi][ni][0] * f0); o.y = f2b(acc[mi][ni][1] * f1);
        o.z = f2b(acc[mi][ni][2] * f2); o.w = f2b(acc[mi][ni][3] * f3);
        *(us4*)&vb[(((b << 4) + h)*64 + d)*2048 + n0] = o;
      }
    }
  } else {
    float sf = (which == 0) ? 0.18033688f : 1.0f;   // 0.125 * log2(e)
    unsigned short* dst = (which == 0) ? qb : kb;
    #pragma unroll
    for (int mi = 0; mi < 4; ++mi){
      #pragma unroll
      for (int j = 0; j < 4; ++j){
        int m = tM*128 + wr + mi*16 + lg*4 + j;
        float f = sf * mWin[m];
        int b = m >> 11, n = m & 2047;
        #pragma unroll
        for (int ni = 0; ni < 4; ++ni){
          int col = c0 + wc + ni*16 + lr;
          int h = col >> 6, d = col & 63;
          dst[(((b << 4) + h)*2048 + n)*64 + d] = f2b(acc[mi][ni][j] * f);
        }
      }
    }
  }
}

// ---------------- attention: split-K (2 halves), 256-row Q tile, 64 q/wave; partial O + den out ----------------
// one tile phase; CUR is a literal 0/1 so all ds_read offsets are immediates.
// kf loaded before QK; vf loaded after (kf dead) to cap peak VGPR.
#define TILE_BODY(CUR, TNEXT, NXT, DO_PF)                                              \
  {                                                                                    \
    if (DO_PF){                                                                        \
      _Pragma("unroll")                                                                \
      for (int r = 0; r < 2; ++r){                                                     \
        gll16(Kg + (TNEXT)*8192 + srow[r]*128 + so[r], ldsK + (NXT)*8192 + r*4096 + wv*1024); \
        gll16(Vg + srow[r]*4096 + (TNEXT)*128 + so[r], ldsV + (NXT)*8192 + r*4096 + wv*1024); \
      }                                                                                \
    }                                                                                  \
    short8v kf[4][2];                                                                  \
    _Pragma("unroll")                                                                  \
    for (int ni = 0; ni < 4; ++ni){                                                    \
      kf[ni][0] = *(const short8v*)(kv0 + (CUR)*8192 + ni*2048);                       \
      kf[ni][1] = *(const short8v*)(kv1 + (CUR)*8192 + ni*2048);                       \
    }                                                                                  \
    f32x4 s[4][4];                                                                     \
    __builtin_amdgcn_s_setprio(1);                                                     \
    _Pragma("unroll")                                                                  \
    for (int mi = 0; mi < 4; ++mi)                                                     \
      _Pragma("unroll")                                                                \
      for (int ni = 0; ni < 4; ++ni){                                                  \
        f32x4 sa = (f32x4){0.f,0.f,0.f,0.f};                                           \
        sa = MFMA(kf[ni][0], qf[mi][0], sa);                                           \
        sa = MFMA(kf[ni][1], qf[mi][1], sa);                                           \
        s[mi][ni] = sa;                                                                \
      }                                                                                \
    __builtin_amdgcn_s_setprio(0);                                                     \
    short8v vf[4][2];                                                                  \
    _Pragma("unroll")                                                                  \
    for (int ni = 0; ni < 4; ++ni){                                                    \
      vf[ni][0] = *(const short8v*)(vv0 + (CUR)*8192 + ni*2048);                       \
      vf[ni][1] = *(const short8v*)(vv1 + (CUR)*8192 + ni*2048);                       \
    }                                                                                  \
    _Pragma("unroll")                                                                  \
    for (int mi = 0; mi < 4; ++mi){                                                    \
      unsigned int R[4][2];                                                            \
      float dl = 0.f;                                                                  \
      _Pragma("unroll")                                                                \
      for (int ni = 0; ni < 4; ++ni){                                                  \
        _Pragma("unroll")                                                              \
        for (int hh = 0; hh < 2; ++hh){                                                \
          float p0 = __builtin_amdgcn_exp2f(s[mi][ni][2*hh]);                          \
          float p1 = __builtin_amdgcn_exp2f(s[mi][ni][2*hh+1]);                        \
          dl += p0 + p1;                                                               \
          R[ni][hh] = cvtpk(p0, p1);                                                   \
        }                                                                              \
      }                                                                                \
      den[mi] += dl;                                                                   \
      pl32swap(R[0][0], R[1][0]); pl16swap(R[0][0], R[1][0]);                          \
      pl32swap(R[0][1], R[1][1]); pl16swap(R[0][1], R[1][1]);                          \
      pl32swap(R[2][0], R[3][0]); pl16swap(R[2][0], R[3][0]);                          \
      pl32swap(R[2][1], R[3][1]); pl16swap(R[2][1], R[3][1]);                          \
      U8 pa0, pa1;                                                                     \
      pa0.u[0] = R[0][0]; pa0.u[1] = R[0][1]; pa0.u[2] = R[1][0]; pa0.u[3] = R[1][1];  \
      pa1.u[0] = R[2][0]; pa1.u[1] = R[2][1]; pa1.u[2] = R[3][0]; pa1.u[3] = R[3][1];  \
      __builtin_amdgcn_s_setprio(1);                                                   \
      _Pragma("unroll")                                                                \
      for (int nf = 0; nf < 4; ++nf){                                                  \
        oacc[mi][nf] = MFMA(pa0.v, vf[nf][0], oacc[mi][nf]);                           \
        oacc[mi][nf] = MFMA(pa1.v, vf[nf][1], oacc[mi][nf]);                           \
      }                                                                                \
      __builtin_amdgcn_s_setprio(0);                                                   \
    }                                                                                  \
    __syncthreads();                                                                   \
  }

__global__ __launch_bounds__(256,2) void attn_k(
  const unsigned short* __restrict__ qbuf,
  const unsigned short* __restrict__ kbuf,
  const unsigned short* __restrict__ vbuf,   // transposed [bh][d][n]
  unsigned short* __restrict__ pO0,          // partial O bf16 [8192][1024], split 0
  unsigned short* __restrict__ pO1,          // split 1
  float* __restrict__ dn)                    // den partials [2][64][2048]
{
  __shared__ unsigned short Ks[2][4096];    // [buf][64 kk][64 d] swizzled
  __shared__ unsigned short Vt[2][4096];    // [buf][64 d][64 kk] swizzled
  // XCD-clustered decode: per XCD 8 bh x 2 sk x 8 qt -> K/V set = 4MB = one L2
  int lin = blockIdx.x;                     // 1024 blocks (4/CU resident at VGPR<=128)
  int xcd = lin & 7, slot = lin >> 3;       // slot in [0,128)
  int qt = slot & 7;                        // 8 q-tiles of 256 rows
  int sk = (slot >> 3) & 1;                 // key-range split
  int bh = xcd + ((slot >> 4) << 3);
  int b = bh >> 4, h = bh & 15;
  const unsigned short* Q  = qbuf + (bh*2048 + qt*256)*64;
  const char* Kg = (const char*)(kbuf + bh*2048*64) + sk*131072;  // rows n (keys), 128B each
  const char* Vg = (const char*)(vbuf + bh*64*2048) + sk*2048;    // rows d, 4096B stride; cols=keys
  unsigned short* po = sk ? pO1 : pO0;
  float* dno = dn + sk*131072 + bh*2048;
  char* ldsK = (char*)Ks; char* ldsV = (char*)Vt;
  int tid = threadIdx.x, lane = tid & 63, wv = tid >> 6;
  int lr = lane & 15, lg = lane >> 4;

  // staging geometry: per wave 2 rounds of 1KB; pre-swizzled global source (rule 21)
  int so[2], srow[2];
  #pragma unroll
  for (int r = 0; r < 2; ++r){
    int o = r*4096 + wv*1024 + lane*16;
    srow[r] = o >> 7;
    so[r] = (o & 127) ^ ((srow[r] & 7) << 4);
  }

  // loop-invariant swizzled read bases
  int lb  = lr*128 + ((lg*16) ^ ((lr&3)<<4));
  int ksA = (lr & 4) << 4;                  // ks=0 term
  const char* kv0 = ldsK + lb + ksA;
  const char* kv1 = ldsK + lb + (64 - ksA); // ks=1 term
  const char* vv0 = ldsV + lb + ksA;
  const char* vv1 = ldsV + lb + (64 - ksA);

  short8v qf[4][2];   // 64 q-rows per wave: rows wv*64 + mi*16 + lr within the 256-row tile
  #pragma unroll
  for (int mi = 0; mi < 4; ++mi)
    #pragma unroll
    for (int ks = 0; ks < 2; ++ks)
      qf[mi][ks] = *(const short8v*)&Q[(wv*64 + mi*16 + lr)*64 + ks*32 + lg*8];

  f32x4 oacc[4][4];
  #pragma unroll
  for (int mi = 0; mi < 4; ++mi)
    #pragma unroll
    for (int nf = 0; nf < 4; ++nf) oacc[mi][nf] = (f32x4){0.f,0.f,0.f,0.f};
  float den[4] = {0.f, 0.f, 0.f, 0.f};

  // prologue: stage tile 0 into buf 0
  #pragma unroll
  for (int r = 0; r < 2; ++r){
    gll16(Kg + srow[r]*128  + so[r], ldsK + r*4096 + wv*1024);
    gll16(Vg + srow[r]*4096 + so[r], ldsV + r*4096 + wv*1024);
  }
  __syncthreads();

  #pragma unroll 1
  for (int tt = 0; tt < 8; ++tt){          // 16 tiles (half the keys)
    int t0 = tt << 1;
    TILE_BODY(0, t0+1, 1, 1)
    TILE_BODY(1, t0+2, 0, (tt < 7))
  }

  // epilogue: complete den partial (sum lg copies), write den + unnormalized O (bf16)
  #pragma unroll
  for (int mi = 0; mi < 4; ++mi){
    float d = den[mi];
    d += __shfl_xor(d, 16, 64);
    d += __shfl_xor(d, 32, 64);
    if (lg == 0) dno[qt*256 + wv*64 + mi*16 + lr] = d;
  }
  #pragma unroll
  for (int mi = 0; mi < 4; ++mi){
    #pragma unroll
    for (int j = 0; j < 4; ++j){
      int n = qt*256 + wv*64 + mi*16 + lg*4 + j;
      #pragma unroll
      for (int nf = 0; nf < 4; ++nf)
        po[(b*2048 + n)*1024 + h*64 + nf*16 + lr] = f2b(oacc[mi][nf][j]);
    }
  }
}

// ---------------- combine: ab = (pO0 + pO1) / ((den0+den1) * (mWin*cnt + eps)) ----------------
__global__ __launch_bounds__(256) void combine_k(
    const unsigned short* __restrict__ pO0, const unsigned short* __restrict__ pO1,
    const float* __restrict__ dn, const float* __restrict__ mWin,
    const float* __restrict__ cnt, unsigned short* __restrict__ ab)
{
  int m = blockIdx.x;                 // b*2048 + n, 8192 blocks
  int b = m >> 11, n = m & 2047;
  int col = threadIdx.x * 4;          // 4 contiguous cols
  int h = col >> 6;
  int bh = (b << 4) + h;
  float den = dn[bh*2048 + n] + dn[131072 + bh*2048 + n];
  float g = 1.0f / (den * (mWin[m] * cnt[b] + 1e-6f));
  us4 a = *(const us4*)&pO0[m*1024 + col];
  us4 c = *(const us4*)&pO1[m*1024 + col];
  us4 o;
  o.x = f2b((b2f(a.x) + b2f(c.x)) * g);
  o.y = f2b((b2f(a.y) + b2f(c.y)) * g);
  o.z = f2b((b2f(a.z) + b2f(c.z)) * g);
  o.w = f2b((b2f(a.w) + b2f(c.w)) * g);
  *(us4*)&ab[m*1024 + col] = o;
}

// ---------------- proj GEMM: ab[8192x1024] @ wproj[1024x1024]^T + bias -> fp32 out ----------------
__global__ __launch_bounds__(256,2) void proj_gemm(
    const unsigned short* __restrict__ abuf,
    const unsigned short* __restrict__ wb,
    const float* __restrict__ pb,
    float* __restrict__ out)
{
  __shared__ unsigned short As[128*64];
  __shared__ unsigned short Bs[128*64];
  int lin = blockIdx.x;                      // 512 blocks
  int swz = (lin & 7) * 64 + (lin >> 3);
  int tM = swz & 63, tN = swz >> 6;          // 64 x 8
  int tid = threadIdx.x, lane = tid & 63, wv = tid >> 6;
  int lr = lane & 15, lg = lane >> 4;

  const unsigned short* ga[4]; const unsigned short* gbp[4];
  char* lA[4]; char* lB[4];
  #pragma unroll
  for (int c = 0; c < 4; ++c){
    int o = c*4096 + wv*1024 + lane*16;
    int row = o >> 7, cole = (o & 127) >> 1;
    ga[c]  = abuf + (tM*128 + row)*1024 + cole;
    gbp[c] = wb   + (tN*128 + row)*1024 + cole;
    lA[c] = (char*)As + c*4096 + wv*1024;
    lB[c] = (char*)Bs + c*4096 + wv*1024;
  }

  f32x4 acc[4][4];
  #pragma unroll
  for (int i = 0; i < 4; ++i)
    #pragma unroll
    for (int j = 0; j < 4; ++j) acc[i][j] = (f32x4){0.f,0.f,0.f,0.f};

  int wr = (wv >> 1) * 64, wc = (wv & 1) * 64;

  for (int it = 0; it < 16; ++it){
    #pragma unroll
    for (int c = 0; c < 4; ++c){
      gll16(ga[c]  + it*64, lA[c]);
      gll16(gbp[c] + it*64, lB[c]);
    }
    __syncthreads();
    short8v af[4][2], bf[4][2];
    #pragma unroll
    for (int mi = 0; mi < 4; ++mi)
      #pragma unroll
      for (int ks = 0; ks < 2; ++ks)
        af[mi][ks] = *(const short8v*)&As[(wr + mi*16 + lr)*64 + ks*32 + lg*8];
    #pragma unroll
    for (int ni = 0; ni < 4; ++ni)
      #pragma unroll
      for (int ks = 0; ks < 2; ++ks)
        bf[ni][ks] = *(const short8v*)&Bs[(wc + ni*16 + lr)*64 + ks*32 + lg*8];
    #pragma unroll
    for (int mi = 0; mi < 4; ++mi)
      #pragma unroll
      for (int ni = 0; ni < 4; ++ni)
        #pragma unroll
        for (int ks = 0; ks < 2; ++ks)
          acc[mi][ni] = MFMA(af[mi][ks], bf[ni][ks], acc[mi][ni]);
    __syncthreads();
  }

  #pragma unroll
  for (int mi = 0; mi < 4; ++mi){
    #pragma unroll
    for (int j = 0; j < 4; ++j){
      int m = tM*128 + wr + mi*16 + lg*4 + j;
      #pragma unroll
      for (int ni = 0; ni < 4; ++ni){
        int col = tN*128 + wc + ni*16 + lr;
        out[m*1024 + col] = acc[mi][ni][j] + pb[col];
      }
    }
  }
}

extern "C" void kernel_launch(void* const* d_in, const int* in_sizes, int n_in,
                              void* d_out, int out_size, void* d_ws, size_t ws_size,
                              hipStream_t stream) {
  const float* x      = (const float*)d_in[0];
  const float* mWin   = (const float*)d_in[1];
  const float* qkv_w  = (const float*)d_in[2];
  const float* proj_w = (const float*)d_in[3];
  const float* proj_b = (const float*)d_in[4];
  float* out = (float*)d_out;
  char* ws = (char*)d_ws;

  // workspace layout (bytes) with region reuse across pipeline stages:
  //   [0,16M):    xb (qkv input)     -> pO0 (attn partial, split 0)
  //   [16M,22M):  wqkvb              -> dn (den partials, 1 MB)
  //   [22M..):    wprojb (2 MB, live until proj)
  //   [25.2M,41.9M): qb              -> ab (combine output, proj input)
  //   [41.9M,58.7M): kb
  //   [58.7M,75.5M): vb (transposed)
  //   d_out[0,16M): pO1 (attn partial, split 1; consumed by combine before proj writes out)
  unsigned short* xb     = (unsigned short*)(ws);                 // 16 MB
  unsigned short* pO0    = (unsigned short*)(ws);                 // alias (xb dead after qkv)
  unsigned short* wqkvb  = (unsigned short*)(ws + 16777216);      //  6 MB
  float*          dn     = (float*)(ws + 16777216);               // alias (wqkvb dead after qkv)
  unsigned short* wprojb = (unsigned short*)(ws + 23068672);      //  2 MB
  unsigned short* qb     = (unsigned short*)(ws + 25165824);      // 16 MB
  unsigned short* ab     = (unsigned short*)(ws + 25165824);      // alias (qb dead after attn)
  unsigned short* kb     = (unsigned short*)(ws + 41943040);      // 16 MB
  unsigned short* vb     = (unsigned short*)(ws + 58720256);      // 16 MB (transposed)
  float* cnt             = (float*)(ws + 75497472);               // 16 B
  unsigned short* pO1    = (unsigned short*)d_out;                // 16 MB of the 32 MB output buffer

  hipMemsetAsync(cnt, 0, 16, stream);
  prep_k<<<12292, 256, 0, stream>>>(x, qkv_w, proj_w, mWin, xb, wqkvb, wprojb, cnt);
  qkv_gemm<<<1536, 256, 0, stream>>>(xb, wqkvb, mWin, qb, kb, vb);
  attn_k<<<1024, 256, 0, stream>>>(qb, kb, vb, pO0, pO1, dn);
  combine_k<<<8192, 256, 0, stream>>>(pO0, pO1, dn, mWin, cnt, ab);
  proj_gemm<<<512, 256, 0, stream>>>(ab, wprojb, proj_b, out);
}

// Round 11
// 193.813 us; speedup vs baseline: 1.0590x; 1.0590x over previous
//
#include <hip/hip_runtime.h>

typedef __attribute__((ext_vector_type(8))) short short8v;
typedef __attribute__((ext_vector_type(4))) float f32x4;
typedef __attribute__((ext_vector_type(4))) unsigned short us4;

#define MFMA(a,b,c) __builtin_amdgcn_mfma_f32_16x16x32_bf16(a,b,c,0,0,0)

__device__ __forceinline__ unsigned short f2b(float f){
  unsigned int u = __float_as_uint(f);
  u += 0x7fffu + ((u >> 16) & 1u);   // round-to-nearest-even
  return (unsigned short)(u >> 16);
}
__device__ __forceinline__ float b2f(unsigned short u){
  return __uint_as_float(((unsigned int)u) << 16);
}

__device__ __forceinline__ void gll16(const void* g, void* l){
  __builtin_amdgcn_global_load_lds((const __attribute__((address_space(1))) void*)g,
                                   (__attribute__((address_space(3))) void*)l, 16, 0, 0);
}

__device__ __forceinline__ unsigned int cvtpk(float lo, float hi){
  unsigned int r;
  asm("v_cvt_pk_bf16_f32 %0, %1, %2" : "=v"(r) : "v"(lo), "v"(hi));
  return r;
}
// a=vdst, b=vsrc. pl32: a'=[a0,a1,b0,b1], b'=[a2,a3,b2,b3] (16-lane rows)
__device__ __forceinline__ void pl32swap(unsigned int &a, unsigned int &b){
  asm("v_permlane32_swap_b32 %0, %1" : "+v"(a), "+v"(b));
}
// pl16: a'=[a0,b0,a2,b2], b'=[a1,b1,a3,b3]
__device__ __forceinline__ void pl16swap(unsigned int &a, unsigned int &b){
  asm("v_permlane16_swap_b32 %0, %1" : "+v"(a), "+v"(b));
}

union U8 { unsigned int u[4]; short8v v; };

// ---------------- fused prep: cast x/qkv_w/proj_w to bf16 + count[b] = sum mWin^2 ----------------
__global__ __launch_bounds__(256) void prep_k(
    const float* __restrict__ x, const float* __restrict__ qkv_w,
    const float* __restrict__ proj_w, const float* __restrict__ mWin,
    unsigned short* __restrict__ xb, unsigned short* __restrict__ wqkvb,
    unsigned short* __restrict__ wprojb, float* __restrict__ cnt){
  int blk = blockIdx.x, tid = threadIdx.x;
  const float* src; unsigned short* dst; int base;
  if (blk < 8192){ src = x; dst = xb; base = 0; }
  else if (blk < 11264){ src = qkv_w; dst = wqkvb; base = 8192; }
  else if (blk < 12288){ src = proj_w; dst = wprojb; base = 11264; }
  else {
    int b = blk - 12288;
    float s = 0.f;
    for (int i = tid; i < 2048; i += 256){ float m = mWin[b*2048 + i]; s += m*m; }
    #pragma unroll
    for (int o = 32; o >= 1; o >>= 1) s += __shfl_xor(s, o, 64);
    if ((tid & 63) == 0) atomicAdd(&cnt[b], s);
    return;
  }
  int i = (blk - base)*256 + tid;
  float4 v = reinterpret_cast<const float4*>(src)[i];
  us4 o; o.x = f2b(v.x); o.y = f2b(v.y); o.z = f2b(v.z); o.w = f2b(v.w);
  reinterpret_cast<us4*>(dst)[i] = o;
}

// ---------------- qkv GEMM: xb[8192x1024] @ wb[3072x1024]^T -> masked/scaled q,k,v bf16 ----------------
// q,k layout: [B*H][N][hd] = [64][2048][64]; v layout TRANSPOSED: [B*H][hd][N] = [64][64][2048]
// q additionally scaled by log2(e) so attention can use exp2 directly.
__global__ __launch_bounds__(256,2) void qkv_gemm(
    const unsigned short* __restrict__ xb,
    const unsigned short* __restrict__ wb,
    const float* __restrict__ mWin,
    unsigned short* __restrict__ qb,
    unsigned short* __restrict__ kb,
    unsigned short* __restrict__ vb)
{
  __shared__ unsigned short As[128*64];
  __shared__ unsigned short Bs[128*64];
  int lin = blockIdx.x;                       // 1536 blocks
  // XCD owns 8 tM rows (2MB A-panel stays L2-resident) and iterates tN:
  int xcd = lin & 7, slot = lin >> 3;         // slot in [0,192)
  int tM = xcd*8 + (slot & 7);                // [0,64)
  int tN = slot >> 3;                         // [0,24)
  int tid = threadIdx.x, lane = tid & 63, wv = tid >> 6;
  int lr = lane & 15, lg = lane >> 4;

  const unsigned short* ga[4]; const unsigned short* gbp[4];
  char* lA[4]; char* lB[4];
  #pragma unroll
  for (int c = 0; c < 4; ++c){
    int o = c*4096 + wv*1024 + lane*16;       // byte offset within 16KB tile
    int row = o >> 7, cole = (o & 127) >> 1;
    ga[c]  = xb + (tM*128 + row)*1024 + cole;
    gbp[c] = wb + (tN*128 + row)*1024 + cole;
    lA[c] = (char*)As + c*4096 + wv*1024;     // wave-uniform LDS base
    lB[c] = (char*)Bs + c*4096 + wv*1024;
  }

  f32x4 acc[4][4];
  #pragma unroll
  for (int i = 0; i < 4; ++i)
    #pragma unroll
    for (int j = 0; j < 4; ++j) acc[i][j] = (f32x4){0.f,0.f,0.f,0.f};

  int wr = (wv >> 1) * 64, wc = (wv & 1) * 64;

  for (int it = 0; it < 16; ++it){
    #pragma unroll
    for (int c = 0; c < 4; ++c){
      gll16(ga[c]  + it*64, lA[c]);
      gll16(gbp[c] + it*64, lB[c]);
    }
    __syncthreads();
    short8v af[4][2], bf[4][2];
    #pragma unroll
    for (int mi = 0; mi < 4; ++mi)
      #pragma unroll
      for (int ks = 0; ks < 2; ++ks)
        af[mi][ks] = *(const short8v*)&As[(wr + mi*16 + lr)*64 + ks*32 + lg*8];
    #pragma unroll
    for (int ni = 0; ni < 4; ++ni)
      #pragma unroll
      for (int ks = 0; ks < 2; ++ks)
        bf[ni][ks] = *(const short8v*)&Bs[(wc + ni*16 + lr)*64 + ks*32 + lg*8];
    #pragma unroll
    for (int mi = 0; mi < 4; ++mi)
      #pragma unroll
      for (int ni = 0; ni < 4; ++ni)
        #pragma unroll
        for (int ks = 0; ks < 2; ++ks)
          acc[mi][ni] = MFMA(af[mi][ks], bf[ni][ks], acc[mi][ni]);
    __syncthreads();
  }

  // epilogue: scatter to q/k/v with mask (+scale*log2e for q); v stored transposed
  int which = tN >> 3;               // 0=q 1=k 2=v (128-col tiles never straddle)
  int c0 = (tN & 7) * 128;
  if (which == 2){
    #pragma unroll
    for (int mi = 0; mi < 4; ++mi){
      int m0 = tM*128 + wr + mi*16 + lg*4;     // m = b*2048 + n, 4 consecutive rows
      int b = m0 >> 11, n0 = m0 & 2047;
      float f0 = mWin[m0], f1 = mWin[m0+1], f2 = mWin[m0+2], f3 = mWin[m0+3];
      #pragma unroll
      for (int ni = 0; ni < 4; ++ni){
        int col = c0 + wc + ni*16 + lr;
        int h = col >> 6, d = col & 63;
        us4 o;
        o.x = f2b(acc[mi][ni][0] * f0); o.y = f2b(acc[mi][ni][1] * f1);
        o.z = f2b(acc[mi][ni][2] * f2); o.w = f2b(acc[mi][ni][3] * f3);
        *(us4*)&vb[(((b << 4) + h)*64 + d)*2048 + n0] = o;
      }
    }
  } else {
    float sf = (which == 0) ? 0.18033688f : 1.0f;   // 0.125 * log2(e)
    unsigned short* dst = (which == 0) ? qb : kb;
    #pragma unroll
    for (int mi = 0; mi < 4; ++mi){
      #pragma unroll
      for (int j = 0; j < 4; ++j){
        int m = tM*128 + wr + mi*16 + lg*4 + j;
        float f = sf * mWin[m];
        int b = m >> 11, n = m & 2047;
        #pragma unroll
        for (int ni = 0; ni < 4; ++ni){
          int col = c0 + wc + ni*16 + lr;
          int h = col >> 6, d = col & 63;
          dst[(((b << 4) + h)*2048 + n)*64 + d] = f2b(acc[mi][ni][j] * f);
        }
      }
    }
  }
}

// ---------------- attention: split-K (2 halves), 256-row Q tile, 64 q/wave; partial O + den out ----------------
// one tile phase; CUR is a literal 0/1 so all ds_read offsets are immediates.
// kf loaded before QK; vf loaded after (kf dead) to cap peak VGPR.
#define TILE_BODY(CUR, TNEXT, NXT, DO_PF)                                              \
  {                                                                                    \
    if (DO_PF){                                                                        \
      _Pragma("unroll")                                                                \
      for (int r = 0; r < 2; ++r){                                                     \
        gll16(Kg + (TNEXT)*8192 + srow[r]*128 + so[r], ldsK + (NXT)*8192 + r*4096 + wv*1024); \
        gll16(Vg + srow[r]*4096 + (TNEXT)*128 + so[r], ldsV + (NXT)*8192 + r*4096 + wv*1024); \
      }                                                                                \
    }                                                                                  \
    short8v kf[4][2];                                                                  \
    _Pragma("unroll")                                                                  \
    for (int ni = 0; ni < 4; ++ni){                                                    \
      kf[ni][0] = *(const short8v*)(kv0 + (CUR)*8192 + ni*2048);                       \
      kf[ni][1] = *(const short8v*)(kv1 + (CUR)*8192 + ni*2048);                       \
    }                                                                                  \
    f32x4 s[4][4];                                                                     \
    __builtin_amdgcn_s_setprio(1);                                                     \
    _Pragma("unroll")                                                                  \
    for (int mi = 0; mi < 4; ++mi)                                                     \
      _Pragma("unroll")                                                                \
      for (int ni = 0; ni < 4; ++ni){                                                  \
        f32x4 sa = (f32x4){0.f,0.f,0.f,0.f};                                           \
        sa = MFMA(kf[ni][0], qf[mi][0], sa);                                           \
        sa = MFMA(kf[ni][1], qf[mi][1], sa);                                           \
        s[mi][ni] = sa;                                                                \
      }                                                                                \
    __builtin_amdgcn_s_setprio(0);                                                     \
    short8v vf[4][2];                                                                  \
    _Pragma("unroll")                                                                  \
    for (int ni = 0; ni < 4; ++ni){                                                    \
      vf[ni][0] = *(const short8v*)(vv0 + (CUR)*8192 + ni*2048);                       \
      vf[ni][1] = *(const short8v*)(vv1 + (CUR)*8192 + ni*2048);                       \
    }                                                                                  \
    _Pragma("unroll")                                                                  \
    for (int mi = 0; mi < 4; ++mi){                                                    \
      unsigned int R[4][2];                                                            \
      float dl = 0.f;                                                                  \
      _Pragma("unroll")                                                                \
      for (int ni = 0; ni < 4; ++ni){                                                  \
        _Pragma("unroll")                                                              \
        for (int hh = 0; hh < 2; ++hh){                                                \
          float p0 = __builtin_amdgcn_exp2f(s[mi][ni][2*hh]);                          \
          float p1 = __builtin_amdgcn_exp2f(s[mi][ni][2*hh+1]);                        \
          dl += p0 + p1;                                                               \
          R[ni][hh] = cvtpk(p0, p1);                                                   \
        }                                                                              \
      }                                                                                \
      den[mi] += dl;                                                                   \
      pl32swap(R[0][0], R[1][0]); pl16swap(R[0][0], R[1][0]);                          \
      pl32swap(R[0][1], R[1][1]); pl16swap(R[0][1], R[1][1]);                          \
      pl32swap(R[2][0], R[3][0]); pl16swap(R[2][0], R[3][0]);                          \
      pl32swap(R[2][1], R[3][1]); pl16swap(R[2][1], R[3][1]);                          \
      U8 pa0, pa1;                                                                     \
      pa0.u[0] = R[0][0]; pa0.u[1] = R[0][1]; pa0.u[2] = R[1][0]; pa0.u[3] = R[1][1];  \
      pa1.u[0] = R[2][0]; pa1.u[1] = R[2][1]; pa1.u[2] = R[3][0]; pa1.u[3] = R[3][1];  \
      __builtin_amdgcn_s_setprio(1);                                                   \
      _Pragma("unroll")                                                                \
      for (int nf = 0; nf < 4; ++nf){                                                  \
        oacc[mi][nf] = MFMA(pa0.v, vf[nf][0], oacc[mi][nf]);                           \
        oacc[mi][nf] = MFMA(pa1.v, vf[nf][1], oacc[mi][nf]);                           \
      }                                                                                \
      __builtin_amdgcn_s_setprio(0);                                                   \
    }                                                                                  \
    __syncthreads();                                                                   \
  }

__global__ __launch_bounds__(256,2) void attn_k(
  const unsigned short* __restrict__ qbuf,
  const unsigned short* __restrict__ kbuf,
  const unsigned short* __restrict__ vbuf,   // transposed [bh][d][n]
  unsigned short* __restrict__ pO0,          // partial O bf16 [8192][1024], split 0
  unsigned short* __restrict__ pO1,          // split 1
  float* __restrict__ dn)                    // den partials [2][64][2048]
{
  __shared__ unsigned short Ks[2][4096];    // [buf][64 kk][64 d] swizzled
  __shared__ unsigned short Vt[2][4096];    // [buf][64 d][64 kk] swizzled
  // XCD-clustered decode: per XCD 8 bh x 2 sk x 8 qt -> K/V set = 4MB = one L2
  int lin = blockIdx.x;                     // 1024 blocks (4/CU resident at VGPR<=128)
  int xcd = lin & 7, slot = lin >> 3;       // slot in [0,128)
  int qt = slot & 7;                        // 8 q-tiles of 256 rows
  int sk = (slot >> 3) & 1;                 // key-range split
  int bh = xcd + ((slot >> 4) << 3);
  int b = bh >> 4, h = bh & 15;
  const unsigned short* Q  = qbuf + (bh*2048 + qt*256)*64;
  const char* Kg = (const char*)(kbuf + bh*2048*64) + sk*131072;  // rows n (keys), 128B each
  const char* Vg = (const char*)(vbuf + bh*64*2048) + sk*2048;    // rows d, 4096B stride; cols=keys
  unsigned short* po = sk ? pO1 : pO0;
  float* dno = dn + sk*131072 + bh*2048;
  char* ldsK = (char*)Ks; char* ldsV = (char*)Vt;
  int tid = threadIdx.x, lane = tid & 63, wv = tid >> 6;
  int lr = lane & 15, lg = lane >> 4;

  // staging geometry: per wave 2 rounds of 1KB; pre-swizzled global source (rule 21)
  int so[2], srow[2];
  #pragma unroll
  for (int r = 0; r < 2; ++r){
    int o = r*4096 + wv*1024 + lane*16;
    srow[r] = o >> 7;
    so[r] = (o & 127) ^ ((srow[r] & 7) << 4);
  }

  // loop-invariant swizzled read bases
  int lb  = lr*128 + ((lg*16) ^ ((lr&3)<<4));
  int ksA = (lr & 4) << 4;                  // ks=0 term
  const char* kv0 = ldsK + lb + ksA;
  const char* kv1 = ldsK + lb + (64 - ksA); // ks=1 term
  const char* vv0 = ldsV + lb + ksA;
  const char* vv1 = ldsV + lb + (64 - ksA);

  short8v qf[4][2];   // 64 q-rows per wave: rows wv*64 + mi*16 + lr within the 256-row tile
  #pragma unroll
  for (int mi = 0; mi < 4; ++mi)
    #pragma unroll
    for (int ks = 0; ks < 2; ++ks)
      qf[mi][ks] = *(const short8v*)&Q[(wv*64 + mi*16 + lr)*64 + ks*32 + lg*8];

  f32x4 oacc[4][4];
  #pragma unroll
  for (int mi = 0; mi < 4; ++mi)
    #pragma unroll
    for (int nf = 0; nf < 4; ++nf) oacc[mi][nf] = (f32x4){0.f,0.f,0.f,0.f};
  float den[4] = {0.f, 0.f, 0.f, 0.f};

  // prologue: stage tile 0 into buf 0
  #pragma unroll
  for (int r = 0; r < 2; ++r){
    gll16(Kg + srow[r]*128  + so[r], ldsK + r*4096 + wv*1024);
    gll16(Vg + srow[r]*4096 + so[r], ldsV + r*4096 + wv*1024);
  }
  __syncthreads();

  #pragma unroll 1
  for (int tt = 0; tt < 8; ++tt){          // 16 tiles (half the keys)
    int t0 = tt << 1;
    TILE_BODY(0, t0+1, 1, 1)
    TILE_BODY(1, t0+2, 0, (tt < 7))
  }

  // epilogue: complete den partial (sum lg copies), write den + unnormalized O (bf16)
  #pragma unroll
  for (int mi = 0; mi < 4; ++mi){
    float d = den[mi];
    d += __shfl_xor(d, 16, 64);
    d += __shfl_xor(d, 32, 64);
    if (lg == 0) dno[qt*256 + wv*64 + mi*16 + lr] = d;
  }
  #pragma unroll
  for (int mi = 0; mi < 4; ++mi){
    #pragma unroll
    for (int j = 0; j < 4; ++j){
      int n = qt*256 + wv*64 + mi*16 + lg*4 + j;
      #pragma unroll
      for (int nf = 0; nf < 4; ++nf)
        po[(b*2048 + n)*1024 + h*64 + nf*16 + lr] = f2b(oacc[mi][nf][j]);
    }
  }
}

// ---------------- combine: ab = (pO0 + pO1) / ((den0+den1) * (mWin*cnt + eps)) ----------------
__global__ __launch_bounds__(256) void combine_k(
    const unsigned short* __restrict__ pO0, const unsigned short* __restrict__ pO1,
    const float* __restrict__ dn, const float* __restrict__ mWin,
    const float* __restrict__ cnt, unsigned short* __restrict__ ab)
{
  int m = blockIdx.x;                 // b*2048 + n, 8192 blocks
  int b = m >> 11, n = m & 2047;
  int col = threadIdx.x * 4;          // 4 contiguous cols
  int h = col >> 6;
  int bh = (b << 4) + h;
  float den = dn[bh*2048 + n] + dn[131072 + bh*2048 + n];
  float g = 1.0f / (den * (mWin[m] * cnt[b] + 1e-6f));
  us4 a = *(const us4*)&pO0[m*1024 + col];
  us4 c = *(const us4*)&pO1[m*1024 + col];
  us4 o;
  o.x = f2b((b2f(a.x) + b2f(c.x)) * g);
  o.y = f2b((b2f(a.y) + b2f(c.y)) * g);
  o.z = f2b((b2f(a.z) + b2f(c.z)) * g);
  o.w = f2b((b2f(a.w) + b2f(c.w)) * g);
  *(us4*)&ab[m*1024 + col] = o;
}

// ---------------- proj GEMM: ab[8192x1024] @ wproj[1024x1024]^T + bias -> fp32 out ----------------
__global__ __launch_bounds__(256,2) void proj_gemm(
    const unsigned short* __restrict__ abuf,
    const unsigned short* __restrict__ wb,
    const float* __restrict__ pb,
    float* __restrict__ out)
{
  __shared__ unsigned short As[128*64];
  __shared__ unsigned short Bs[128*64];
  int lin = blockIdx.x;                      // 512 blocks
  // XCD owns 8 tM rows (A-panel L2-resident), iterates tN:
  int xcd = lin & 7, slot = lin >> 3;        // slot in [0,64)
  int tM = xcd*8 + (slot & 7);               // [0,64)
  int tN = slot >> 3;                        // [0,8)
  int tid = threadIdx.x, lane = tid & 63, wv = tid >> 6;
  int lr = lane & 15, lg = lane >> 4;

  const unsigned short* ga[4]; const unsigned short* gbp[4];
  char* lA[4]; char* lB[4];
  #pragma unroll
  for (int c = 0; c < 4; ++c){
    int o = c*4096 + wv*1024 + lane*16;
    int row = o >> 7, cole = (o & 127) >> 1;
    ga[c]  = abuf + (tM*128 + row)*1024 + cole;
    gbp[c] = wb   + (tN*128 + row)*1024 + cole;
    lA[c] = (char*)As + c*4096 + wv*1024;
    lB[c] = (char*)Bs + c*4096 + wv*1024;
  }

  f32x4 acc[4][4];
  #pragma unroll
  for (int i = 0; i < 4; ++i)
    #pragma unroll
    for (int j = 0; j < 4; ++j) acc[i][j] = (f32x4){0.f,0.f,0.f,0.f};

  int wr = (wv >> 1) * 64, wc = (wv & 1) * 64;

  for (int it = 0; it < 16; ++it){
    #pragma unroll
    for (int c = 0; c < 4; ++c){
      gll16(ga[c]  + it*64, lA[c]);
      gll16(gbp[c] + it*64, lB[c]);
    }
    __syncthreads();
    short8v af[4][2], bf[4][2];
    #pragma unroll
    for (int mi = 0; mi < 4; ++mi)
      #pragma unroll
      for (int ks = 0; ks < 2; ++ks)
        af[mi][ks] = *(const short8v*)&As[(wr + mi*16 + lr)*64 + ks*32 + lg*8];
    #pragma unroll
    for (int ni = 0; ni < 4; ++ni)
      #pragma unroll
      for (int ks = 0; ks < 2; ++ks)
        bf[ni][ks] = *(const short8v*)&Bs[(wc + ni*16 + lr)*64 + ks*32 + lg*8];
    #pragma unroll
    for (int mi = 0; mi < 4; ++mi)
      #pragma unroll
      for (int ni = 0; ni < 4; ++ni)
        #pragma unroll
        for (int ks = 0; ks < 2; ++ks)
          acc[mi][ni] = MFMA(af[mi][ks], bf[ni][ks], acc[mi][ni]);
    __syncthreads();
  }

  #pragma unroll
  for (int mi = 0; mi < 4; ++mi){
    #pragma unroll
    for (int j = 0; j < 4; ++j){
      int m = tM*128 + wr + mi*16 + lg*4 + j;
      #pragma unroll
      for (int ni = 0; ni < 4; ++ni){
        int col = tN*128 + wc + ni*16 + lr;
        out[m*1024 + col] = acc[mi][ni][j] + pb[col];
      }
    }
  }
}

extern "C" void kernel_launch(void* const* d_in, const int* in_sizes, int n_in,
                              void* d_out, int out_size, void* d_ws, size_t ws_size,
                              hipStream_t stream) {
  const float* x      = (const float*)d_in[0];
  const float* mWin   = (const float*)d_in[1];
  const float* qkv_w  = (const float*)d_in[2];
  const float* proj_w = (const float*)d_in[3];
  const float* proj_b = (const float*)d_in[4];
  float* out = (float*)d_out;
  char* ws = (char*)d_ws;

  // workspace layout (bytes) with region reuse across pipeline stages:
  //   [0,16M):    xb (qkv input)     -> pO0 (attn partial, split 0)
  //   [16M,22M):  wqkvb              -> dn (den partials, 1 MB)
  //   [22M..):    wprojb (2 MB, live until proj)
  //   [25.2M,41.9M): qb              -> ab (combine output, proj input)
  //   [41.9M,58.7M): kb
  //   [58.7M,75.5M): vb (transposed)
  //   d_out[0,16M): pO1 (attn partial, split 1; consumed by combine before proj writes out)
  unsigned short* xb     = (unsigned short*)(ws);                 // 16 MB
  unsigned short* pO0    = (unsigned short*)(ws);                 // alias (xb dead after qkv)
  unsigned short* wqkvb  = (unsigned short*)(ws + 16777216);      //  6 MB
  float*          dn     = (float*)(ws + 16777216);               // alias (wqkvb dead after qkv)
  unsigned short* wprojb = (unsigned short*)(ws + 23068672);      //  2 MB
  unsigned short* qb     = (unsigned short*)(ws + 25165824);      // 16 MB
  unsigned short* ab     = (unsigned short*)(ws + 25165824);      // alias (qb dead after attn)
  unsigned short* kb     = (unsigned short*)(ws + 41943040);      // 16 MB
  unsigned short* vb     = (unsigned short*)(ws + 58720256);      // 16 MB (transposed)
  float* cnt             = (float*)(ws + 75497472);               // 16 B
  unsigned short* pO1    = (unsigned short*)d_out;                // 16 MB of the 32 MB output buffer

  hipMemsetAsync(cnt, 0, 16, stream);
  prep_k<<<12292, 256, 0, stream>>>(x, qkv_w, proj_w, mWin, xb, wqkvb, wprojb, cnt);
  qkv_gemm<<<1536, 256, 0, stream>>>(xb, wqkvb, mWin, qb, kb, vb);
  attn_k<<<1024, 256, 0, stream>>>(qb, kb, vb, pO0, pO1, dn);
  combine_k<<<8192, 256, 0, stream>>>(pO0, pO1, dn, mWin, cnt, ab);
  proj_gemm<<<512, 256, 0, stream>>>(ab, wprojb, proj_b, out);
}

// Round 12
// 185.078 us; speedup vs baseline: 1.1090x; 1.0472x over previous
//
#include <hip/hip_runtime.h>

typedef __attribute__((ext_vector_type(8))) short short8v;
typedef __attribute__((ext_vector_type(4))) float f32x4;
typedef __attribute__((ext_vector_type(4))) unsigned short us4;

#define MFMA(a,b,c) __builtin_amdgcn_mfma_f32_16x16x32_bf16(a,b,c,0,0,0)

__device__ __forceinline__ unsigned short f2b(float f){
  unsigned int u = __float_as_uint(f);
  u += 0x7fffu + ((u >> 16) & 1u);   // round-to-nearest-even
  return (unsigned short)(u >> 16);
}

__device__ __forceinline__ void gll16(const void* g, void* l){
  __builtin_amdgcn_global_load_lds((const __attribute__((address_space(1))) void*)g,
                                   (__attribute__((address_space(3))) void*)l, 16, 0, 0);
}

__device__ __forceinline__ unsigned int cvtpk(float lo, float hi){
  unsigned int r;
  asm("v_cvt_pk_bf16_f32 %0, %1, %2" : "=v"(r) : "v"(lo), "v"(hi));
  return r;
}
// a=vdst, b=vsrc. pl32: a'=[a0,a1,b0,b1], b'=[a2,a3,b2,b3] (16-lane rows)
__device__ __forceinline__ void pl32swap(unsigned int &a, unsigned int &b){
  asm("v_permlane32_swap_b32 %0, %1" : "+v"(a), "+v"(b));
}
// pl16: a'=[a0,b0,a2,b2], b'=[a1,b1,a3,b3]
__device__ __forceinline__ void pl16swap(unsigned int &a, unsigned int &b){
  asm("v_permlane16_swap_b32 %0, %1" : "+v"(a), "+v"(b));
}

union U8 { unsigned int u[4]; short8v v; };

// ---------------- fused prep: cast x/qkv_w/proj_w to bf16 + count[b] = sum mWin^2 ----------------
__global__ __launch_bounds__(256) void prep_k(
    const float* __restrict__ x, const float* __restrict__ qkv_w,
    const float* __restrict__ proj_w, const float* __restrict__ mWin,
    unsigned short* __restrict__ xb, unsigned short* __restrict__ wqkvb,
    unsigned short* __restrict__ wprojb, float* __restrict__ cnt){
  int blk = blockIdx.x, tid = threadIdx.x;
  const float* src; unsigned short* dst; int base;
  if (blk < 8192){ src = x; dst = xb; base = 0; }
  else if (blk < 11264){ src = qkv_w; dst = wqkvb; base = 8192; }
  else if (blk < 12288){ src = proj_w; dst = wprojb; base = 11264; }
  else {
    int b = blk - 12288;
    float s = 0.f;
    for (int i = tid; i < 2048; i += 256){ float m = mWin[b*2048 + i]; s += m*m; }
    #pragma unroll
    for (int o = 32; o >= 1; o >>= 1) s += __shfl_xor(s, o, 64);
    if ((tid & 63) == 0) atomicAdd(&cnt[b], s);
    return;
  }
  int i = (blk - base)*256 + tid;
  float4 v = reinterpret_cast<const float4*>(src)[i];
  us4 o; o.x = f2b(v.x); o.y = f2b(v.y); o.z = f2b(v.z); o.w = f2b(v.w);
  reinterpret_cast<us4*>(dst)[i] = o;
}

// ---------------- qkv GEMM: xb[8192x1024] @ wb[3072x1024]^T -> masked/scaled q,k,v bf16 ----------------
// q,k layout: [B*H][N][hd] = [64][2048][64]; v layout TRANSPOSED: [B*H][hd][N] = [64][64][2048]
// q additionally scaled by log2(e) so attention can use exp2 directly.
__global__ __launch_bounds__(256,2) void qkv_gemm(
    const unsigned short* __restrict__ xb,
    const unsigned short* __restrict__ wb,
    const float* __restrict__ mWin,
    unsigned short* __restrict__ qb,
    unsigned short* __restrict__ kb,
    unsigned short* __restrict__ vb)
{
  __shared__ unsigned short As[128*64];
  __shared__ unsigned short Bs[128*64];
  int lin = blockIdx.x;                       // 1536 blocks
  // XCD owns 8 tM rows (2MB A-panel stays L2-resident) and iterates tN:
  int xcd = lin & 7, slot = lin >> 3;         // slot in [0,192)
  int tM = xcd*8 + (slot & 7);                // [0,64)
  int tN = slot >> 3;                         // [0,24)
  int tid = threadIdx.x, lane = tid & 63, wv = tid >> 6;
  int lr = lane & 15, lg = lane >> 4;

  const unsigned short* ga[4]; const unsigned short* gbp[4];
  char* lA[4]; char* lB[4];
  #pragma unroll
  for (int c = 0; c < 4; ++c){
    int o = c*4096 + wv*1024 + lane*16;       // byte offset within 16KB tile
    int row = o >> 7, cole = (o & 127) >> 1;
    ga[c]  = xb + (tM*128 + row)*1024 + cole;
    gbp[c] = wb + (tN*128 + row)*1024 + cole;
    lA[c] = (char*)As + c*4096 + wv*1024;     // wave-uniform LDS base
    lB[c] = (char*)Bs + c*4096 + wv*1024;
  }

  f32x4 acc[4][4];
  #pragma unroll
  for (int i = 0; i < 4; ++i)
    #pragma unroll
    for (int j = 0; j < 4; ++j) acc[i][j] = (f32x4){0.f,0.f,0.f,0.f};

  int wr = (wv >> 1) * 64, wc = (wv & 1) * 64;

  for (int it = 0; it < 16; ++it){
    #pragma unroll
    for (int c = 0; c < 4; ++c){
      gll16(ga[c]  + it*64, lA[c]);
      gll16(gbp[c] + it*64, lB[c]);
    }
    __syncthreads();
    short8v af[4][2], bf[4][2];
    #pragma unroll
    for (int mi = 0; mi < 4; ++mi)
      #pragma unroll
      for (int ks = 0; ks < 2; ++ks)
        af[mi][ks] = *(const short8v*)&As[(wr + mi*16 + lr)*64 + ks*32 + lg*8];
    #pragma unroll
    for (int ni = 0; ni < 4; ++ni)
      #pragma unroll
      for (int ks = 0; ks < 2; ++ks)
        bf[ni][ks] = *(const short8v*)&Bs[(wc + ni*16 + lr)*64 + ks*32 + lg*8];
    #pragma unroll
    for (int mi = 0; mi < 4; ++mi)
      #pragma unroll
      for (int ni = 0; ni < 4; ++ni)
        #pragma unroll
        for (int ks = 0; ks < 2; ++ks)
          acc[mi][ni] = MFMA(af[mi][ks], bf[ni][ks], acc[mi][ni]);
    __syncthreads();
  }

  // epilogue: scatter to q/k/v with mask (+scale*log2e for q); v stored transposed
  int which = tN >> 3;               // 0=q 1=k 2=v (128-col tiles never straddle)
  int c0 = (tN & 7) * 128;
  if (which == 2){
    #pragma unroll
    for (int mi = 0; mi < 4; ++mi){
      int m0 = tM*128 + wr + mi*16 + lg*4;     // m = b*2048 + n, 4 consecutive rows
      int b = m0 >> 11, n0 = m0 & 2047;
      float f0 = mWin[m0], f1 = mWin[m0+1], f2 = mWin[m0+2], f3 = mWin[m0+3];
      #pragma unroll
      for (int ni = 0; ni < 4; ++ni){
        int col = c0 + wc + ni*16 + lr;
        int h = col >> 6, d = col & 63;
        us4 o;
        o.x = f2b(acc[mi][ni][0] * f0); o.y = f2b(acc[mi][ni][1] * f1);
        o.z = f2b(acc[mi][ni][2] * f2); o.w = f2b(acc[mi][ni][3] * f3);
        *(us4*)&vb[(((b << 4) + h)*64 + d)*2048 + n0] = o;
      }
    }
  } else {
    float sf = (which == 0) ? 0.18033688f : 1.0f;   // 0.125 * log2(e)
    unsigned short* dst = (which == 0) ? qb : kb;
    #pragma unroll
    for (int mi = 0; mi < 4; ++mi){
      #pragma unroll
      for (int j = 0; j < 4; ++j){
        int m = tM*128 + wr + mi*16 + lg*4 + j;
        float f = sf * mWin[m];
        int b = m >> 11, n = m & 2047;
        #pragma unroll
        for (int ni = 0; ni < 4; ++ni){
          int col = c0 + wc + ni*16 + lr;
          int h = col >> 6, d = col & 63;
          dst[(((b << 4) + h)*2048 + n)*64 + d] = f2b(acc[mi][ni][j] * f);
        }
      }
    }
  }
}

// ---------------- attention: 256-row Q tile, 64 q-rows/wave (mi<4); direct normalized write ----------------
// one tile phase; CUR is a literal 0/1 so all ds_read offsets are immediates.
// kf loaded before QK; vf loaded after (kf dead) to cap peak VGPR.
#define TILE_BODY(CUR, TNEXT, NXT, DO_PF)                                              \
  {                                                                                    \
    if (DO_PF){                                                                        \
      _Pragma("unroll")                                                                \
      for (int r = 0; r < 2; ++r){                                                     \
        gll16(Kg + (TNEXT)*8192 + srow[r]*128 + so[r], ldsK + (NXT)*8192 + r*4096 + wv*1024); \
        gll16(Vg + srow[r]*4096 + (TNEXT)*128 + so[r], ldsV + (NXT)*8192 + r*4096 + wv*1024); \
      }                                                                                \
    }                                                                                  \
    short8v kf[4][2];                                                                  \
    _Pragma("unroll")                                                                  \
    for (int ni = 0; ni < 4; ++ni){                                                    \
      kf[ni][0] = *(const short8v*)(kv0 + (CUR)*8192 + ni*2048);                       \
      kf[ni][1] = *(const short8v*)(kv1 + (CUR)*8192 + ni*2048);                       \
    }                                                                                  \
    f32x4 s[4][4];                                                                     \
    __builtin_amdgcn_s_setprio(1);                                                     \
    _Pragma("unroll")                                                                  \
    for (int mi = 0; mi < 4; ++mi)                                                     \
      _Pragma("unroll")                                                                \
      for (int ni = 0; ni < 4; ++ni){                                                  \
        f32x4 sa = (f32x4){0.f,0.f,0.f,0.f};                                           \
        sa = MFMA(kf[ni][0], qf[mi][0], sa);                                           \
        sa = MFMA(kf[ni][1], qf[mi][1], sa);                                           \
        s[mi][ni] = sa;                                                                \
      }                                                                                \
    __builtin_amdgcn_s_setprio(0);                                                     \
    short8v vf[4][2];                                                                  \
    _Pragma("unroll")                                                                  \
    for (int ni = 0; ni < 4; ++ni){                                                    \
      vf[ni][0] = *(const short8v*)(vv0 + (CUR)*8192 + ni*2048);                       \
      vf[ni][1] = *(const short8v*)(vv1 + (CUR)*8192 + ni*2048);                       \
    }                                                                                  \
    _Pragma("unroll")                                                                  \
    for (int mi = 0; mi < 4; ++mi){                                                    \
      unsigned int R[4][2];                                                            \
      float dl = 0.f;                                                                  \
      _Pragma("unroll")                                                                \
      for (int ni = 0; ni < 4; ++ni){                                                  \
        _Pragma("unroll")                                                              \
        for (int hh = 0; hh < 2; ++hh){                                                \
          float p0 = __builtin_amdgcn_exp2f(s[mi][ni][2*hh]);                          \
          float p1 = __builtin_amdgcn_exp2f(s[mi][ni][2*hh+1]);                        \
          dl += p0 + p1;                                                               \
          R[ni][hh] = cvtpk(p0, p1);                                                   \
        }                                                                              \
      }                                                                                \
      den[mi] += dl;                                                                   \
      pl32swap(R[0][0], R[1][0]); pl16swap(R[0][0], R[1][0]);                          \
      pl32swap(R[0][1], R[1][1]); pl16swap(R[0][1], R[1][1]);                          \
      pl32swap(R[2][0], R[3][0]); pl16swap(R[2][0], R[3][0]);                          \
      pl32swap(R[2][1], R[3][1]); pl16swap(R[2][1], R[3][1]);                          \
      U8 pa0, pa1;                                                                     \
      pa0.u[0] = R[0][0]; pa0.u[1] = R[0][1]; pa0.u[2] = R[1][0]; pa0.u[3] = R[1][1];  \
      pa1.u[0] = R[2][0]; pa1.u[1] = R[2][1]; pa1.u[2] = R[3][0]; pa1.u[3] = R[3][1];  \
      __builtin_amdgcn_s_setprio(1);                                                   \
      _Pragma("unroll")                                                                \
      for (int nf = 0; nf < 4; ++nf){                                                  \
        oacc[mi][nf] = MFMA(pa0.v, vf[nf][0], oacc[mi][nf]);                           \
        oacc[mi][nf] = MFMA(pa1.v, vf[nf][1], oacc[mi][nf]);                           \
      }                                                                                \
      __builtin_amdgcn_s_setprio(0);                                                   \
    }                                                                                  \
    __syncthreads();                                                                   \
  }

__global__ __launch_bounds__(256,2) void attn_k(
  const unsigned short* __restrict__ qbuf,
  const unsigned short* __restrict__ kbuf,
  const unsigned short* __restrict__ vbuf,   // transposed [bh][d][n]
  const float* __restrict__ mWin,
  const float* __restrict__ cnt,
  unsigned short* __restrict__ ab)
{
  __shared__ unsigned short Ks[2][4096];    // [buf][64 kk][64 d] swizzled
  __shared__ unsigned short Vt[2][4096];    // [buf][64 d][64 kk] swizzled
  // XCD-clustered decode: 8 qt-blocks x 8 bh per XCD -> K/V set = 4MB = one L2
  int lin = blockIdx.x;                     // 512 blocks (2/CU, all co-resident)
  int xcd = lin & 7, slot = lin >> 3;       // slot in [0,64)
  int qt = slot & 7;                        // 8 q-tiles of 256 rows
  int bh = xcd + ((slot >> 3) << 3);
  int b = bh >> 4, h = bh & 15;
  const unsigned short* Q  = qbuf + (bh*2048 + qt*256)*64;
  const char* Kg = (const char*)(kbuf + bh*2048*64);      // rows n, 128B, contiguous
  const char* Vg = (const char*)(vbuf + bh*64*2048);      // rows d, 4096B stride
  char* ldsK = (char*)Ks; char* ldsV = (char*)Vt;
  int tid = threadIdx.x, lane = tid & 63, wv = tid >> 6;
  int lr = lane & 15, lg = lane >> 4;

  // staging geometry: per wave 2 rounds of 1KB; pre-swizzled global source (rule 21)
  int so[2], srow[2];
  #pragma unroll
  for (int r = 0; r < 2; ++r){
    int o = r*4096 + wv*1024 + lane*16;
    srow[r] = o >> 7;
    so[r] = (o & 127) ^ ((srow[r] & 7) << 4);
  }

  // loop-invariant swizzled read bases:
  // byte(row=ni*16+lr, inrow=ks*64+lg*16) = ni*2048 + lr*128 + ((lg*16)^((lr&3)<<4)) + ((ks*64)^((lr&4)<<4))
  int lb  = lr*128 + ((lg*16) ^ ((lr&3)<<4));
  int ksA = (lr & 4) << 4;                  // ks=0 term
  const char* kv0 = ldsK + lb + ksA;
  const char* kv1 = ldsK + lb + (64 - ksA); // ks=1 term
  const char* vv0 = ldsV + lb + ksA;
  const char* vv1 = ldsV + lb + (64 - ksA);

  short8v qf[4][2];   // 64 q-rows per wave: rows wv*64 + mi*16 + lr within the 256-row tile
  #pragma unroll
  for (int mi = 0; mi < 4; ++mi)
    #pragma unroll
    for (int ks = 0; ks < 2; ++ks)
      qf[mi][ks] = *(const short8v*)&Q[(wv*64 + mi*16 + lr)*64 + ks*32 + lg*8];

  f32x4 oacc[4][4];
  #pragma unroll
  for (int mi = 0; mi < 4; ++mi)
    #pragma unroll
    for (int nf = 0; nf < 4; ++nf) oacc[mi][nf] = (f32x4){0.f,0.f,0.f,0.f};
  float den[4] = {0.f, 0.f, 0.f, 0.f};   // per-lane partial for q = wv*64 + mi*16 + lr

  // prologue: stage tile 0 into buf 0
  #pragma unroll
  for (int r = 0; r < 2; ++r){
    gll16(Kg + srow[r]*128  + so[r], ldsK + r*4096 + wv*1024);
    gll16(Vg + srow[r]*4096 + so[r], ldsV + r*4096 + wv*1024);
  }
  __syncthreads();

  #pragma unroll 1
  for (int tt = 0; tt < 16; ++tt){
    int t0 = tt << 1;
    TILE_BODY(0, t0+1, 1, 1)
    TILE_BODY(1, t0+2, 0, (tt < 15))
  }

  // epilogue: complete den (sum across lg copies), redistribute to C-layout rows, store
  #pragma unroll
  for (int mi = 0; mi < 4; ++mi){
    float d = den[mi];
    d += __shfl_xor(d, 16, 64);
    d += __shfl_xor(d, 32, 64);
    den[mi] = d;                 // lane (lr,lg) now holds full den for q=wv*64+mi*16+lr
  }
  #pragma unroll
  for (int mi = 0; mi < 4; ++mi){
    #pragma unroll
    for (int j = 0; j < 4; ++j){
      float dd = __shfl(den[mi], lg*4 + j, 64);   // den for q-row lg*4+j (lane lr==lg*4+j)
      int n = qt*256 + wv*64 + mi*16 + lg*4 + j;
      float mv = mWin[b*2048 + n];
      float g = 1.0f / (dd * (mv * cnt[b] + 1e-6f));
      #pragma unroll
      for (int nf = 0; nf < 4; ++nf)
        ab[(b*2048 + n)*1024 + h*64 + nf*16 + lr] = f2b(oacc[mi][nf][j] * g);
    }
  }
}

// ---------------- proj GEMM: ab[8192x1024] @ wproj[1024x1024]^T + bias -> fp32 out ----------------
__global__ __launch_bounds__(256,2) void proj_gemm(
    const unsigned short* __restrict__ abuf,
    const unsigned short* __restrict__ wb,
    const float* __restrict__ pb,
    float* __restrict__ out)
{
  __shared__ unsigned short As[128*64];
  __shared__ unsigned short Bs[128*64];
  int lin = blockIdx.x;                      // 512 blocks
  // XCD owns 8 tM rows (A-panel L2-resident), iterates tN:
  int xcd = lin & 7, slot = lin >> 3;        // slot in [0,64)
  int tM = xcd*8 + (slot & 7);               // [0,64)
  int tN = slot >> 3;                        // [0,8)
  int tid = threadIdx.x, lane = tid & 63, wv = tid >> 6;
  int lr = lane & 15, lg = lane >> 4;

  const unsigned short* ga[4]; const unsigned short* gbp[4];
  char* lA[4]; char* lB[4];
  #pragma unroll
  for (int c = 0; c < 4; ++c){
    int o = c*4096 + wv*1024 + lane*16;
    int row = o >> 7, cole = (o & 127) >> 1;
    ga[c]  = abuf + (tM*128 + row)*1024 + cole;
    gbp[c] = wb   + (tN*128 + row)*1024 + cole;
    lA[c] = (char*)As + c*4096 + wv*1024;
    lB[c] = (char*)Bs + c*4096 + wv*1024;
  }

  f32x4 acc[4][4];
  #pragma unroll
  for (int i = 0; i < 4; ++i)
    #pragma unroll
    for (int j = 0; j < 4; ++j) acc[i][j] = (f32x4){0.f,0.f,0.f,0.f};

  int wr = (wv >> 1) * 64, wc = (wv & 1) * 64;

  for (int it = 0; it < 16; ++it){
    #pragma unroll
    for (int c = 0; c < 4; ++c){
      gll16(ga[c]  + it*64, lA[c]);
      gll16(gbp[c] + it*64, lB[c]);
    }
    __syncthreads();
    short8v af[4][2], bf[4][2];
    #pragma unroll
    for (int mi = 0; mi < 4; ++mi)
      #pragma unroll
      for (int ks = 0; ks < 2; ++ks)
        af[mi][ks] = *(const short8v*)&As[(wr + mi*16 + lr)*64 + ks*32 + lg*8];
    #pragma unroll
    for (int ni = 0; ni < 4; ++ni)
      #pragma unroll
      for (int ks = 0; ks < 2; ++ks)
        bf[ni][ks] = *(const short8v*)&Bs[(wc + ni*16 + lr)*64 + ks*32 + lg*8];
    #pragma unroll
    for (int mi = 0; mi < 4; ++mi)
      #pragma unroll
      for (int ni = 0; ni < 4; ++ni)
        #pragma unroll
        for (int ks = 0; ks < 2; ++ks)
          acc[mi][ni] = MFMA(af[mi][ks], bf[ni][ks], acc[mi][ni]);
    __syncthreads();
  }

  #pragma unroll
  for (int mi = 0; mi < 4; ++mi){
    #pragma unroll
    for (int j = 0; j < 4; ++j){
      int m = tM*128 + wr + mi*16 + lg*4 + j;
      #pragma unroll
      for (int ni = 0; ni < 4; ++ni){
        int col = tN*128 + wc + ni*16 + lr;
        out[m*1024 + col] = acc[mi][ni][j] + pb[col];
      }
    }
  }
}

extern "C" void kernel_launch(void* const* d_in, const int* in_sizes, int n_in,
                              void* d_out, int out_size, void* d_ws, size_t ws_size,
                              hipStream_t stream) {
  const float* x      = (const float*)d_in[0];
  const float* mWin   = (const float*)d_in[1];
  const float* qkv_w  = (const float*)d_in[2];
  const float* proj_w = (const float*)d_in[3];
  const float* proj_b = (const float*)d_in[4];
  float* out = (float*)d_out;
  char* ws = (char*)d_ws;

  // workspace layout (bytes); ab aliases xb (xb dead after qkv_gemm)
  unsigned short* xb     = (unsigned short*)(ws);                 // 16 MB
  unsigned short* ab     = (unsigned short*)(ws);                 // alias
  unsigned short* wqkvb  = (unsigned short*)(ws + 16777216);      //  6 MB
  unsigned short* wprojb = (unsigned short*)(ws + 23068672);      //  2 MB
  unsigned short* qb     = (unsigned short*)(ws + 25165824);      // 16 MB
  unsigned short* kb     = (unsigned short*)(ws + 41943040);      // 16 MB
  unsigned short* vb     = (unsigned short*)(ws + 58720256);      // 16 MB (transposed)
  float* cnt             = (float*)(ws + 75497472);               // 16 B

  hipMemsetAsync(cnt, 0, 16, stream);
  prep_k<<<12292, 256, 0, stream>>>(x, qkv_w, proj_w, mWin, xb, wqkvb, wprojb, cnt);
  qkv_gemm<<<1536, 256, 0, stream>>>(xb, wqkvb, mWin, qb, kb, vb);
  attn_k<<<512, 256, 0, stream>>>(qb, kb, vb, mWin, cnt, ab);
  proj_gemm<<<512, 256, 0, stream>>>(ab, wprojb, proj_b, out);
}

// Round 13
// 178.984 us; speedup vs baseline: 1.1468x; 1.0340x over previous
//
#include <hip/hip_runtime.h>

typedef __attribute__((ext_vector_type(8))) short short8v;
typedef __attribute__((ext_vector_type(4))) float f32x4;
typedef __attribute__((ext_vector_type(4))) unsigned short us4;

#define MFMA(a,b,c) __builtin_amdgcn_mfma_f32_16x16x32_bf16(a,b,c,0,0,0)

__device__ __forceinline__ unsigned short f2b(float f){
  unsigned int u = __float_as_uint(f);
  u += 0x7fffu + ((u >> 16) & 1u);   // round-to-nearest-even
  return (unsigned short)(u >> 16);
}

__device__ __forceinline__ void gll16(const void* g, void* l){
  __builtin_amdgcn_global_load_lds((const __attribute__((address_space(1))) void*)g,
                                   (__attribute__((address_space(3))) void*)l, 16, 0, 0);
}

__device__ __forceinline__ unsigned int cvtpk(float lo, float hi){
  unsigned int r;
  asm("v_cvt_pk_bf16_f32 %0, %1, %2" : "=v"(r) : "v"(lo), "v"(hi));
  return r;
}
// a=vdst, b=vsrc. pl32: a'=[a0,a1,b0,b1], b'=[a2,a3,b2,b3] (16-lane rows)
__device__ __forceinline__ void pl32swap(unsigned int &a, unsigned int &b){
  asm("v_permlane32_swap_b32 %0, %1" : "+v"(a), "+v"(b));
}
// pl16: a'=[a0,b0,a2,b2], b'=[a1,b1,a3,b3]
__device__ __forceinline__ void pl16swap(unsigned int &a, unsigned int &b){
  asm("v_permlane16_swap_b32 %0, %1" : "+v"(a), "+v"(b));
}

union U8 { unsigned int u[4]; short8v v; };

// ---------------- fused prep: cast x/qkv_w/proj_w to bf16 (4 float4/thread) + cnt[b] = sum mWin^2 ----------------
// grid = 2048 + 768 + 256 + 4 = 3076 blocks
__global__ __launch_bounds__(256) void prep_k(
    const float* __restrict__ x, const float* __restrict__ qkv_w,
    const float* __restrict__ proj_w, const float* __restrict__ mWin,
    unsigned short* __restrict__ xb, unsigned short* __restrict__ wqkvb,
    unsigned short* __restrict__ wprojb, float* __restrict__ cnt){
  __shared__ float ws4[4];
  int blk = blockIdx.x, tid = threadIdx.x;
  const float* src; unsigned short* dst; int base;
  if (blk < 2048){ src = x; dst = xb; base = 0; }
  else if (blk < 2816){ src = qkv_w; dst = wqkvb; base = 2048; }
  else if (blk < 3072){ src = proj_w; dst = wprojb; base = 2816; }
  else {
    int b = blk - 3072;
    float s = 0.f;
    for (int i = tid; i < 2048; i += 256){ float m = mWin[b*2048 + i]; s += m*m; }
    #pragma unroll
    for (int o = 32; o >= 1; o >>= 1) s += __shfl_xor(s, o, 64);
    if ((tid & 63) == 0) ws4[tid >> 6] = s;
    __syncthreads();
    if (tid == 0) cnt[b] = ws4[0] + ws4[1] + ws4[2] + ws4[3];
    return;
  }
  int i0 = (blk - base)*1024 + tid;
  #pragma unroll
  for (int r = 0; r < 4; ++r){
    int i = i0 + r*256;
    float4 v = reinterpret_cast<const float4*>(src)[i];
    us4 o; o.x = f2b(v.x); o.y = f2b(v.y); o.z = f2b(v.z); o.w = f2b(v.w);
    reinterpret_cast<us4*>(dst)[i] = o;
  }
}

// ---------------- qkv GEMM: xb[8192x1024] @ wb[3072x1024]^T -> masked/scaled q,k,v bf16 ----------------
// q,k layout: [B*H][N][hd] = [64][2048][64]; v layout TRANSPOSED: [B*H][hd][N] = [64][64][2048]
// q additionally scaled by log2(e) so attention can use exp2 directly.
__global__ __launch_bounds__(256,2) void qkv_gemm(
    const unsigned short* __restrict__ xb,
    const unsigned short* __restrict__ wb,
    const float* __restrict__ mWin,
    unsigned short* __restrict__ qb,
    unsigned short* __restrict__ kb,
    unsigned short* __restrict__ vb)
{
  __shared__ unsigned short As[128*64];
  __shared__ unsigned short Bs[128*64];
  int lin = blockIdx.x;                       // 1536 blocks
  // XCD owns 8 tM rows (2MB A-panel stays L2-resident) and iterates tN:
  int xcd = lin & 7, slot = lin >> 3;         // slot in [0,192)
  int tM = xcd*8 + (slot & 7);                // [0,64)
  int tN = slot >> 3;                         // [0,24)
  int tid = threadIdx.x, lane = tid & 63, wv = tid >> 6;
  int lr = lane & 15, lg = lane >> 4;

  const unsigned short* ga[4]; const unsigned short* gbp[4];
  char* lA[4]; char* lB[4];
  #pragma unroll
  for (int c = 0; c < 4; ++c){
    int o = c*4096 + wv*1024 + lane*16;       // byte offset within 16KB tile
    int row = o >> 7, cole = (o & 127) >> 1;
    ga[c]  = xb + (tM*128 + row)*1024 + cole;
    gbp[c] = wb + (tN*128 + row)*1024 + cole;
    lA[c] = (char*)As + c*4096 + wv*1024;     // wave-uniform LDS base
    lB[c] = (char*)Bs + c*4096 + wv*1024;
  }

  f32x4 acc[4][4];
  #pragma unroll
  for (int i = 0; i < 4; ++i)
    #pragma unroll
    for (int j = 0; j < 4; ++j) acc[i][j] = (f32x4){0.f,0.f,0.f,0.f};

  int wr = (wv >> 1) * 64, wc = (wv & 1) * 64;

  for (int it = 0; it < 16; ++it){
    #pragma unroll
    for (int c = 0; c < 4; ++c){
      gll16(ga[c]  + it*64, lA[c]);
      gll16(gbp[c] + it*64, lB[c]);
    }
    __syncthreads();
    short8v af[4][2], bf[4][2];
    #pragma unroll
    for (int mi = 0; mi < 4; ++mi)
      #pragma unroll
      for (int ks = 0; ks < 2; ++ks)
        af[mi][ks] = *(const short8v*)&As[(wr + mi*16 + lr)*64 + ks*32 + lg*8];
    #pragma unroll
    for (int ni = 0; ni < 4; ++ni)
      #pragma unroll
      for (int ks = 0; ks < 2; ++ks)
        bf[ni][ks] = *(const short8v*)&Bs[(wc + ni*16 + lr)*64 + ks*32 + lg*8];
    #pragma unroll
    for (int mi = 0; mi < 4; ++mi)
      #pragma unroll
      for (int ni = 0; ni < 4; ++ni)
        #pragma unroll
        for (int ks = 0; ks < 2; ++ks)
          acc[mi][ni] = MFMA(af[mi][ks], bf[ni][ks], acc[mi][ni]);
    __syncthreads();
  }

  // epilogue: scatter to q/k/v with mask (+scale*log2e for q); v stored transposed
  int which = tN >> 3;               // 0=q 1=k 2=v (128-col tiles never straddle)
  int c0 = (tN & 7) * 128;
  if (which == 2){
    #pragma unroll
    for (int mi = 0; mi < 4; ++mi){
      int m0 = tM*128 + wr + mi*16 + lg*4;     // m = b*2048 + n, 4 consecutive rows
      int b = m0 >> 11, n0 = m0 & 2047;
      float f0 = mWin[m0], f1 = mWin[m0+1], f2 = mWin[m0+2], f3 = mWin[m0+3];
      #pragma unroll
      for (int ni = 0; ni < 4; ++ni){
        int col = c0 + wc + ni*16 + lr;
        int h = col >> 6, d = col & 63;
        us4 o;
        o.x = f2b(acc[mi][ni][0] * f0); o.y = f2b(acc[mi][ni][1] * f1);
        o.z = f2b(acc[mi][ni][2] * f2); o.w = f2b(acc[mi][ni][3] * f3);
        *(us4*)&vb[(((b << 4) + h)*64 + d)*2048 + n0] = o;
      }
    }
  } else {
    float sf = (which == 0) ? 0.18033688f : 1.0f;   // 0.125 * log2(e)
    unsigned short* dst = (which == 0) ? qb : kb;
    #pragma unroll
    for (int mi = 0; mi < 4; ++mi){
      #pragma unroll
      for (int j = 0; j < 4; ++j){
        int m = tM*128 + wr + mi*16 + lg*4 + j;
        float f = sf * mWin[m];
        int b = m >> 11, n = m & 2047;
        #pragma unroll
        for (int ni = 0; ni < 4; ++ni){
          int col = c0 + wc + ni*16 + lr;
          int h = col >> 6, d = col & 63;
          dst[(((b << 4) + h)*2048 + n)*64 + d] = f2b(acc[mi][ni][j] * f);
        }
      }
    }
  }
}

// ---------------- attention: 256-row Q tile, 64 q-rows/wave (mi<4); direct normalized write ----------------
// one tile phase; CUR is a literal 0/1 so all ds_read offsets are immediates.
// kf loaded before QK; vf loaded after (kf dead) to cap peak VGPR.
#define TILE_BODY(CUR, TNEXT, NXT, DO_PF)                                              \
  {                                                                                    \
    if (DO_PF){                                                                        \
      _Pragma("unroll")                                                                \
      for (int r = 0; r < 2; ++r){                                                     \
        gll16(Kg + (TNEXT)*8192 + srow[r]*128 + so[r], ldsK + (NXT)*8192 + r*4096 + wv*1024); \
        gll16(Vg + srow[r]*4096 + (TNEXT)*128 + so[r], ldsV + (NXT)*8192 + r*4096 + wv*1024); \
      }                                                                                \
    }                                                                                  \
    short8v kf[4][2];                                                                  \
    _Pragma("unroll")                                                                  \
    for (int ni = 0; ni < 4; ++ni){                                                    \
      kf[ni][0] = *(const short8v*)(kv0 + (CUR)*8192 + ni*2048);                       \
      kf[ni][1] = *(const short8v*)(kv1 + (CUR)*8192 + ni*2048);                       \
    }                                                                                  \
    f32x4 s[4][4];                                                                     \
    __builtin_amdgcn_s_setprio(1);                                                     \
    _Pragma("unroll")                                                                  \
    for (int mi = 0; mi < 4; ++mi)                                                     \
      _Pragma("unroll")                                                                \
      for (int ni = 0; ni < 4; ++ni){                                                  \
        f32x4 sa = (f32x4){0.f,0.f,0.f,0.f};                                           \
        sa = MFMA(kf[ni][0], qf[mi][0], sa);                                           \
        sa = MFMA(kf[ni][1], qf[mi][1], sa);                                           \
        s[mi][ni] = sa;                                                                \
      }                                                                                \
    __builtin_amdgcn_s_setprio(0);                                                     \
    short8v vf[4][2];                                                                  \
    _Pragma("unroll")                                                                  \
    for (int ni = 0; ni < 4; ++ni){                                                    \
      vf[ni][0] = *(const short8v*)(vv0 + (CUR)*8192 + ni*2048);                       \
      vf[ni][1] = *(const short8v*)(vv1 + (CUR)*8192 + ni*2048);                       \
    }                                                                                  \
    _Pragma("unroll")                                                                  \
    for (int mi = 0; mi < 4; ++mi){                                                    \
      unsigned int R[4][2];                                                            \
      float dl = 0.f;                                                                  \
      _Pragma("unroll")                                                                \
      for (int ni = 0; ni < 4; ++ni){                                                  \
        _Pragma("unroll")                                                              \
        for (int hh = 0; hh < 2; ++hh){                                                \
          float p0 = __builtin_amdgcn_exp2f(s[mi][ni][2*hh]);                          \
          float p1 = __builtin_amdgcn_exp2f(s[mi][ni][2*hh+1]);                        \
          dl += p0 + p1;                                                               \
          R[ni][hh] = cvtpk(p0, p1);                                                   \
        }                                                                              \
      }                                                                                \
      den[mi] += dl;                                                                   \
      pl32swap(R[0][0], R[1][0]); pl16swap(R[0][0], R[1][0]);                          \
      pl32swap(R[0][1], R[1][1]); pl16swap(R[0][1], R[1][1]);                          \
      pl32swap(R[2][0], R[3][0]); pl16swap(R[2][0], R[3][0]);                          \
      pl32swap(R[2][1], R[3][1]); pl16swap(R[2][1], R[3][1]);                          \
      U8 pa0, pa1;                                                                     \
      pa0.u[0] = R[0][0]; pa0.u[1] = R[0][1]; pa0.u[2] = R[1][0]; pa0.u[3] = R[1][1];  \
      pa1.u[0] = R[2][0]; pa1.u[1] = R[2][1]; pa1.u[2] = R[3][0]; pa1.u[3] = R[3][1];  \
      __builtin_amdgcn_s_setprio(1);                                                   \
      _Pragma("unroll")                                                                \
      for (int nf = 0; nf < 4; ++nf){                                                  \
        oacc[mi][nf] = MFMA(pa0.v, vf[nf][0], oacc[mi][nf]);                           \
        oacc[mi][nf] = MFMA(pa1.v, vf[nf][1], oacc[mi][nf]);                           \
      }                                                                                \
      __builtin_amdgcn_s_setprio(0);                                                   \
    }                                                                                  \
    __syncthreads();                                                                   \
  }

__global__ __launch_bounds__(256,2) void attn_k(
  const unsigned short* __restrict__ qbuf,
  const unsigned short* __restrict__ kbuf,
  const unsigned short* __restrict__ vbuf,   // transposed [bh][d][n]
  const float* __restrict__ mWin,
  const float* __restrict__ cnt,
  unsigned short* __restrict__ ab)
{
  __shared__ unsigned short Ks[2][4096];    // [buf][64 kk][64 d] swizzled
  __shared__ unsigned short Vt[2][4096];    // [buf][64 d][64 kk] swizzled
  // XCD-clustered decode: 8 qt-blocks x 8 bh per XCD -> K/V set = 4MB = one L2
  int lin = blockIdx.x;                     // 512 blocks (2/CU, all co-resident)
  int xcd = lin & 7, slot = lin >> 3;       // slot in [0,64)
  int qt = slot & 7;                        // 8 q-tiles of 256 rows
  int bh = xcd + ((slot >> 3) << 3);
  int b = bh >> 4, h = bh & 15;
  const unsigned short* Q  = qbuf + (bh*2048 + qt*256)*64;
  const char* Kg = (const char*)(kbuf + bh*2048*64);      // rows n, 128B, contiguous
  const char* Vg = (const char*)(vbuf + bh*64*2048);      // rows d, 4096B stride
  char* ldsK = (char*)Ks; char* ldsV = (char*)Vt;
  int tid = threadIdx.x, lane = tid & 63, wv = tid >> 6;
  int lr = lane & 15, lg = lane >> 4;

  // staging geometry: per wave 2 rounds of 1KB; pre-swizzled global source (rule 21)
  int so[2], srow[2];
  #pragma unroll
  for (int r = 0; r < 2; ++r){
    int o = r*4096 + wv*1024 + lane*16;
    srow[r] = o >> 7;
    so[r] = (o & 127) ^ ((srow[r] & 7) << 4);
  }

  // loop-invariant swizzled read bases:
  // byte(row=ni*16+lr, inrow=ks*64+lg*16) = ni*2048 + lr*128 + ((lg*16)^((lr&3)<<4)) + ((ks*64)^((lr&4)<<4))
  int lb  = lr*128 + ((lg*16) ^ ((lr&3)<<4));
  int ksA = (lr & 4) << 4;                  // ks=0 term
  const char* kv0 = ldsK + lb + ksA;
  const char* kv1 = ldsK + lb + (64 - ksA); // ks=1 term
  const char* vv0 = ldsV + lb + ksA;
  const char* vv1 = ldsV + lb + (64 - ksA);

  short8v qf[4][2];   // 64 q-rows per wave: rows wv*64 + mi*16 + lr within the 256-row tile
  #pragma unroll
  for (int mi = 0; mi < 4; ++mi)
    #pragma unroll
    for (int ks = 0; ks < 2; ++ks)
      qf[mi][ks] = *(const short8v*)&Q[(wv*64 + mi*16 + lr)*64 + ks*32 + lg*8];

  f32x4 oacc[4][4];
  #pragma unroll
  for (int mi = 0; mi < 4; ++mi)
    #pragma unroll
    for (int nf = 0; nf < 4; ++nf) oacc[mi][nf] = (f32x4){0.f,0.f,0.f,0.f};
  float den[4] = {0.f, 0.f, 0.f, 0.f};   // per-lane partial for q = wv*64 + mi*16 + lr

  // prologue: stage tile 0 into buf 0
  #pragma unroll
  for (int r = 0; r < 2; ++r){
    gll16(Kg + srow[r]*128  + so[r], ldsK + r*4096 + wv*1024);
    gll16(Vg + srow[r]*4096 + so[r], ldsV + r*4096 + wv*1024);
  }
  __syncthreads();

  #pragma unroll 1
  for (int tt = 0; tt < 16; ++tt){
    int t0 = tt << 1;
    TILE_BODY(0, t0+1, 1, 1)
    TILE_BODY(1, t0+2, 0, (tt < 15))
  }

  // epilogue: complete den (sum across lg copies), redistribute to C-layout rows, store
  #pragma unroll
  for (int mi = 0; mi < 4; ++mi){
    float d = den[mi];
    d += __shfl_xor(d, 16, 64);
    d += __shfl_xor(d, 32, 64);
    den[mi] = d;                 // lane (lr,lg) now holds full den for q=wv*64+mi*16+lr
  }
  #pragma unroll
  for (int mi = 0; mi < 4; ++mi){
    #pragma unroll
    for (int j = 0; j < 4; ++j){
      float dd = __shfl(den[mi], lg*4 + j, 64);   // den for q-row lg*4+j (lane lr==lg*4+j)
      int n = qt*256 + wv*64 + mi*16 + lg*4 + j;
      float mv = mWin[b*2048 + n];
      float g = 1.0f / (dd * (mv * cnt[b] + 1e-6f));
      #pragma unroll
      for (int nf = 0; nf < 4; ++nf)
        ab[(b*2048 + n)*1024 + h*64 + nf*16 + lr] = f2b(oacc[mi][nf][j] * g);
    }
  }
}

// ---------------- proj GEMM: ab[8192x1024] @ wproj[1024x1024]^T + bias -> fp32 out ----------------
__global__ __launch_bounds__(256,2) void proj_gemm(
    const unsigned short* __restrict__ abuf,
    const unsigned short* __restrict__ wb,
    const float* __restrict__ pb,
    float* __restrict__ out)
{
  __shared__ unsigned short As[128*64];
  __shared__ unsigned short Bs[128*64];
  int lin = blockIdx.x;                      // 512 blocks
  // XCD owns 8 tM rows (A-panel L2-resident), iterates tN:
  int xcd = lin & 7, slot = lin >> 3;        // slot in [0,64)
  int tM = xcd*8 + (slot & 7);               // [0,64)
  int tN = slot >> 3;                        // [0,8)
  int tid = threadIdx.x, lane = tid & 63, wv = tid >> 6;
  int lr = lane & 15, lg = lane >> 4;

  const unsigned short* ga[4]; const unsigned short* gbp[4];
  char* lA[4]; char* lB[4];
  #pragma unroll
  for (int c = 0; c < 4; ++c){
    int o = c*4096 + wv*1024 + lane*16;
    int row = o >> 7, cole = (o & 127) >> 1;
    ga[c]  = abuf + (tM*128 + row)*1024 + cole;
    gbp[c] = wb   + (tN*128 + row)*1024 + cole;
    lA[c] = (char*)As + c*4096 + wv*1024;
    lB[c] = (char*)Bs + c*4096 + wv*1024;
  }

  f32x4 acc[4][4];
  #pragma unroll
  for (int i = 0; i < 4; ++i)
    #pragma unroll
    for (int j = 0; j < 4; ++j) acc[i][j] = (f32x4){0.f,0.f,0.f,0.f};

  int wr = (wv >> 1) * 64, wc = (wv & 1) * 64;

  for (int it = 0; it < 16; ++it){
    #pragma unroll
    for (int c = 0; c < 4; ++c){
      gll16(ga[c]  + it*64, lA[c]);
      gll16(gbp[c] + it*64, lB[c]);
    }
    __syncthreads();
    short8v af[4][2], bf[4][2];
    #pragma unroll
    for (int mi = 0; mi < 4; ++mi)
      #pragma unroll
      for (int ks = 0; ks < 2; ++ks)
        af[mi][ks] = *(const short8v*)&As[(wr + mi*16 + lr)*64 + ks*32 + lg*8];
    #pragma unroll
    for (int ni = 0; ni < 4; ++ni)
      #pragma unroll
      for (int ks = 0; ks < 2; ++ks)
        bf[ni][ks] = *(const short8v*)&Bs[(wc + ni*16 + lr)*64 + ks*32 + lg*8];
    #pragma unroll
    for (int mi = 0; mi < 4; ++mi)
      #pragma unroll
      for (int ni = 0; ni < 4; ++ni)
        #pragma unroll
        for (int ks = 0; ks < 2; ++ks)
          acc[mi][ni] = MFMA(af[mi][ks], bf[ni][ks], acc[mi][ni]);
    __syncthreads();
  }

  #pragma unroll
  for (int mi = 0; mi < 4; ++mi){
    #pragma unroll
    for (int j = 0; j < 4; ++j){
      int m = tM*128 + wr + mi*16 + lg*4 + j;
      #pragma unroll
      for (int ni = 0; ni < 4; ++ni){
        int col = tN*128 + wc + ni*16 + lr;
        out[m*1024 + col] = acc[mi][ni][j] + pb[col];
      }
    }
  }
}

extern "C" void kernel_launch(void* const* d_in, const int* in_sizes, int n_in,
                              void* d_out, int out_size, void* d_ws, size_t ws_size,
                              hipStream_t stream) {
  const float* x      = (const float*)d_in[0];
  const float* mWin   = (const float*)d_in[1];
  const float* qkv_w  = (const float*)d_in[2];
  const float* proj_w = (const float*)d_in[3];
  const float* proj_b = (const float*)d_in[4];
  float* out = (float*)d_out;
  char* ws = (char*)d_ws;

  // workspace layout (bytes); ab aliases xb (xb dead after qkv_gemm)
  unsigned short* xb     = (unsigned short*)(ws);                 // 16 MB
  unsigned short* ab     = (unsigned short*)(ws);                 // alias
  unsigned short* wqkvb  = (unsigned short*)(ws + 16777216);      //  6 MB
  unsigned short* wprojb = (unsigned short*)(ws + 23068672);      //  2 MB
  unsigned short* qb     = (unsigned short*)(ws + 25165824);      // 16 MB
  unsigned short* kb     = (unsigned short*)(ws + 41943040);      // 16 MB
  unsigned short* vb     = (unsigned short*)(ws + 58720256);      // 16 MB (transposed)
  float* cnt             = (float*)(ws + 75497472);               // 16 B

  prep_k<<<3076, 256, 0, stream>>>(x, qkv_w, proj_w, mWin, xb, wqkvb, wprojb, cnt);
  qkv_gemm<<<1536, 256, 0, stream>>>(xb, wqkvb, mWin, qb, kb, vb);
  attn_k<<<512, 256, 0, stream>>>(qb, kb, vb, mWin, cnt, ab);
  proj_gemm<<<512, 256, 0, stream>>>(ab, wprojb, proj_b, out);
}

// Round 14
// 178.741 us; speedup vs baseline: 1.1483x; 1.0014x over previous
//
#include <hip/hip_runtime.h>

typedef __attribute__((ext_vector_type(8))) short short8v;
typedef __attribute__((ext_vector_type(4))) float f32x4;
typedef __attribute__((ext_vector_type(4))) unsigned short us4;

#define MFMA(a,b,c) __builtin_amdgcn_mfma_f32_16x16x32_bf16(a,b,c,0,0,0)

__device__ __forceinline__ unsigned short f2b(float f){
  unsigned int u = __float_as_uint(f);
  u += 0x7fffu + ((u >> 16) & 1u);   // round-to-nearest-even
  return (unsigned short)(u >> 16);
}

__device__ __forceinline__ void gll16(const void* g, void* l){
  __builtin_amdgcn_global_load_lds((const __attribute__((address_space(1))) void*)g,
                                   (__attribute__((address_space(3))) void*)l, 16, 0, 0);
}

__device__ __forceinline__ unsigned int cvtpk(float lo, float hi){
  unsigned int r;
  asm("v_cvt_pk_bf16_f32 %0, %1, %2" : "=v"(r) : "v"(lo), "v"(hi));
  return r;
}
// a=vdst, b=vsrc. pl32: a'=[a0,a1,b0,b1], b'=[a2,a3,b2,b3] (16-lane rows)
__device__ __forceinline__ void pl32swap(unsigned int &a, unsigned int &b){
  asm("v_permlane32_swap_b32 %0, %1" : "+v"(a), "+v"(b));
}
// pl16: a'=[a0,b0,a2,b2], b'=[a1,b1,a3,b3]
__device__ __forceinline__ void pl16swap(unsigned int &a, unsigned int &b){
  asm("v_permlane16_swap_b32 %0, %1" : "+v"(a), "+v"(b));
}

union U8 { unsigned int u[4]; short8v v; };

// ---------------- fused prep: cast x/qkv_w/proj_w to bf16 (4 float4/thread) + cnt[b] = sum mWin^2 ----------------
// grid = 2048 + 768 + 256 + 4 = 3076 blocks
__global__ __launch_bounds__(256) void prep_k(
    const float* __restrict__ x, const float* __restrict__ qkv_w,
    const float* __restrict__ proj_w, const float* __restrict__ mWin,
    unsigned short* __restrict__ xb, unsigned short* __restrict__ wqkvb,
    unsigned short* __restrict__ wprojb, float* __restrict__ cnt){
  __shared__ float ws4[4];
  int blk = blockIdx.x, tid = threadIdx.x;
  const float* src; unsigned short* dst; int base;
  if (blk < 2048){ src = x; dst = xb; base = 0; }
  else if (blk < 2816){ src = qkv_w; dst = wqkvb; base = 2048; }
  else if (blk < 3072){ src = proj_w; dst = wprojb; base = 2816; }
  else {
    int b = blk - 3072;
    float s = 0.f;
    for (int i = tid; i < 2048; i += 256){ float m = mWin[b*2048 + i]; s += m*m; }
    #pragma unroll
    for (int o = 32; o >= 1; o >>= 1) s += __shfl_xor(s, o, 64);
    if ((tid & 63) == 0) ws4[tid >> 6] = s;
    __syncthreads();
    if (tid == 0) cnt[b] = ws4[0] + ws4[1] + ws4[2] + ws4[3];
    return;
  }
  int i0 = (blk - base)*1024 + tid;
  #pragma unroll
  for (int r = 0; r < 4; ++r){
    int i = i0 + r*256;
    float4 v = reinterpret_cast<const float4*>(src)[i];
    us4 o; o.x = f2b(v.x); o.y = f2b(v.y); o.z = f2b(v.z); o.w = f2b(v.w);
    reinterpret_cast<us4*>(dst)[i] = o;
  }
}

// ---------------- qkv GEMM: xb[8192x1024] @ wb[3072x1024]^T -> masked/scaled q,k,v bf16 ----------------
// q,k layout: [B*H][N][hd] = [64][2048][64]; v layout TRANSPOSED: [B*H][hd][N] = [64][64][2048]
// q additionally scaled by log2(e) so attention can use exp2 directly.
// regs: ~60 VGPR + 64 acc = 124 <= 170 (3 waves/SIMD budget) -> 3 blocks/CU, 2 clean rounds of the
// 6-blocks/CU grid (was 3 rounds at 2-resident).
__global__ __launch_bounds__(256,3) void qkv_gemm(
    const unsigned short* __restrict__ xb,
    const unsigned short* __restrict__ wb,
    const float* __restrict__ mWin,
    unsigned short* __restrict__ qb,
    unsigned short* __restrict__ kb,
    unsigned short* __restrict__ vb)
{
  __shared__ unsigned short As[128*64];
  __shared__ unsigned short Bs[128*64];
  int lin = blockIdx.x;                       // 1536 blocks
  // XCD owns 8 tM rows (2MB A-panel stays L2-resident) and iterates tN:
  int xcd = lin & 7, slot = lin >> 3;         // slot in [0,192)
  int tM = xcd*8 + (slot & 7);                // [0,64)
  int tN = slot >> 3;                         // [0,24)
  int tid = threadIdx.x, lane = tid & 63, wv = tid >> 6;
  int lr = lane & 15, lg = lane >> 4;

  const unsigned short* ga[4]; const unsigned short* gbp[4];
  char* lA[4]; char* lB[4];
  #pragma unroll
  for (int c = 0; c < 4; ++c){
    int o = c*4096 + wv*1024 + lane*16;       // byte offset within 16KB tile
    int row = o >> 7, cole = (o & 127) >> 1;
    ga[c]  = xb + (tM*128 + row)*1024 + cole;
    gbp[c] = wb + (tN*128 + row)*1024 + cole;
    lA[c] = (char*)As + c*4096 + wv*1024;     // wave-uniform LDS base
    lB[c] = (char*)Bs + c*4096 + wv*1024;
  }

  f32x4 acc[4][4];
  #pragma unroll
  for (int i = 0; i < 4; ++i)
    #pragma unroll
    for (int j = 0; j < 4; ++j) acc[i][j] = (f32x4){0.f,0.f,0.f,0.f};

  int wr = (wv >> 1) * 64, wc = (wv & 1) * 64;

  for (int it = 0; it < 16; ++it){
    #pragma unroll
    for (int c = 0; c < 4; ++c){
      gll16(ga[c]  + it*64, lA[c]);
      gll16(gbp[c] + it*64, lB[c]);
    }
    __syncthreads();
    short8v af[4][2], bf[4][2];
    #pragma unroll
    for (int mi = 0; mi < 4; ++mi)
      #pragma unroll
      for (int ks = 0; ks < 2; ++ks)
        af[mi][ks] = *(const short8v*)&As[(wr + mi*16 + lr)*64 + ks*32 + lg*8];
    #pragma unroll
    for (int ni = 0; ni < 4; ++ni)
      #pragma unroll
      for (int ks = 0; ks < 2; ++ks)
        bf[ni][ks] = *(const short8v*)&Bs[(wc + ni*16 + lr)*64 + ks*32 + lg*8];
    #pragma unroll
    for (int mi = 0; mi < 4; ++mi)
      #pragma unroll
      for (int ni = 0; ni < 4; ++ni)
        #pragma unroll
        for (int ks = 0; ks < 2; ++ks)
          acc[mi][ni] = MFMA(af[mi][ks], bf[ni][ks], acc[mi][ni]);
    __syncthreads();
  }

  // epilogue: scatter to q/k/v with mask (+scale*log2e for q); v stored transposed
  int which = tN >> 3;               // 0=q 1=k 2=v (128-col tiles never straddle)
  int c0 = (tN & 7) * 128;
  if (which == 2){
    #pragma unroll
    for (int mi = 0; mi < 4; ++mi){
      int m0 = tM*128 + wr + mi*16 + lg*4;     // m = b*2048 + n, 4 consecutive rows
      int b = m0 >> 11, n0 = m0 & 2047;
      float f0 = mWin[m0], f1 = mWin[m0+1], f2 = mWin[m0+2], f3 = mWin[m0+3];
      #pragma unroll
      for (int ni = 0; ni < 4; ++ni){
        int col = c0 + wc + ni*16 + lr;
        int h = col >> 6, d = col & 63;
        us4 o;
        o.x = f2b(acc[mi][ni][0] * f0); o.y = f2b(acc[mi][ni][1] * f1);
        o.z = f2b(acc[mi][ni][2] * f2); o.w = f2b(acc[mi][ni][3] * f3);
        *(us4*)&vb[(((b << 4) + h)*64 + d)*2048 + n0] = o;
      }
    }
  } else {
    float sf = (which == 0) ? 0.18033688f : 1.0f;   // 0.125 * log2(e)
    unsigned short* dst = (which == 0) ? qb : kb;
    #pragma unroll
    for (int mi = 0; mi < 4; ++mi){
      #pragma unroll
      for (int j = 0; j < 4; ++j){
        int m = tM*128 + wr + mi*16 + lg*4 + j;
        float f = sf * mWin[m];
        int b = m >> 11, n = m & 2047;
        #pragma unroll
        for (int ni = 0; ni < 4; ++ni){
          int col = c0 + wc + ni*16 + lr;
          int h = col >> 6, d = col & 63;
          dst[(((b << 4) + h)*2048 + n)*64 + d] = f2b(acc[mi][ni][j] * f);
        }
      }
    }
  }
}

// ---------------- attention: 256-row Q tile, 64 q-rows/wave (mi<4); direct normalized write ----------------
// one tile phase; CUR is a literal 0/1 so all ds_read offsets are immediates.
// kf loaded before QK; vf loaded after (kf dead) to cap peak VGPR.
#define TILE_BODY(CUR, TNEXT, NXT, DO_PF)                                              \
  {                                                                                    \
    if (DO_PF){                                                                        \
      _Pragma("unroll")                                                                \
      for (int r = 0; r < 2; ++r){                                                     \
        gll16(Kg + (TNEXT)*8192 + srow[r]*128 + so[r], ldsK + (NXT)*8192 + r*4096 + wv*1024); \
        gll16(Vg + srow[r]*4096 + (TNEXT)*128 + so[r], ldsV + (NXT)*8192 + r*4096 + wv*1024); \
      }                                                                                \
    }                                                                                  \
    short8v kf[4][2];                                                                  \
    _Pragma("unroll")                                                                  \
    for (int ni = 0; ni < 4; ++ni){                                                    \
      kf[ni][0] = *(const short8v*)(kv0 + (CUR)*8192 + ni*2048);                       \
      kf[ni][1] = *(const short8v*)(kv1 + (CUR)*8192 + ni*2048);                       \
    }                                                                                  \
    f32x4 s[4][4];                                                                     \
    __builtin_amdgcn_s_setprio(1);                                                     \
    _Pragma("unroll")                                                                  \
    for (int mi = 0; mi < 4; ++mi)                                                     \
      _Pragma("unroll")                                                                \
      for (int ni = 0; ni < 4; ++ni){                                                  \
        f32x4 sa = (f32x4){0.f,0.f,0.f,0.f};                                           \
        sa = MFMA(kf[ni][0], qf[mi][0], sa);                                           \
        sa = MFMA(kf[ni][1], qf[mi][1], sa);                                           \
        s[mi][ni] = sa;                                                                \
      }                                                                                \
    __builtin_amdgcn_s_setprio(0);                                                     \
    short8v vf[4][2];                                                                  \
    _Pragma("unroll")                                                                  \
    for (int ni = 0; ni < 4; ++ni){                                                    \
      vf[ni][0] = *(const short8v*)(vv0 + (CUR)*8192 + ni*2048);                       \
      vf[ni][1] = *(const short8v*)(vv1 + (CUR)*8192 + ni*2048);                       \
    }                                                                                  \
    _Pragma("unroll")                                                                  \
    for (int mi = 0; mi < 4; ++mi){                                                    \
      unsigned int R[4][2];                                                            \
      float dl = 0.f;                                                                  \
      _Pragma("unroll")                                                                \
      for (int ni = 0; ni < 4; ++ni){                                                  \
        _Pragma("unroll")                                                              \
        for (int hh = 0; hh < 2; ++hh){                                                \
          float p0 = __builtin_amdgcn_exp2f(s[mi][ni][2*hh]);                          \
          float p1 = __builtin_amdgcn_exp2f(s[mi][ni][2*hh+1]);                        \
          dl += p0 + p1;                                                               \
          R[ni][hh] = cvtpk(p0, p1);                                                   \
        }                                                                              \
      }                                                                                \
      den[mi] += dl;                                                                   \
      pl32swap(R[0][0], R[1][0]); pl16swap(R[0][0], R[1][0]);                          \
      pl32swap(R[0][1], R[1][1]); pl16swap(R[0][1], R[1][1]);                          \
      pl32swap(R[2][0], R[3][0]); pl16swap(R[2][0], R[3][0]);                          \
      pl32swap(R[2][1], R[3][1]); pl16swap(R[2][1], R[3][1]);                          \
      U8 pa0, pa1;                                                                     \
      pa0.u[0] = R[0][0]; pa0.u[1] = R[0][1]; pa0.u[2] = R[1][0]; pa0.u[3] = R[1][1];  \
      pa1.u[0] = R[2][0]; pa1.u[1] = R[2][1]; pa1.u[2] = R[3][0]; pa1.u[3] = R[3][1];  \
      __builtin_amdgcn_s_setprio(1);                                                   \
      _Pragma("unroll")                                                                \
      for (int nf = 0; nf < 4; ++nf){                                                  \
        oacc[mi][nf] = MFMA(pa0.v, vf[nf][0], oacc[mi][nf]);                           \
        oacc[mi][nf] = MFMA(pa1.v, vf[nf][1], oacc[mi][nf]);                           \
      }                                                                                \
      __builtin_amdgcn_s_setprio(0);                                                   \
    }                                                                                  \
    __syncthreads();                                                                   \
  }

__global__ __launch_bounds__(256,2) void attn_k(
  const unsigned short* __restrict__ qbuf,
  const unsigned short* __restrict__ kbuf,
  const unsigned short* __restrict__ vbuf,   // transposed [bh][d][n]
  const float* __restrict__ mWin,
  const float* __restrict__ cnt,
  unsigned short* __restrict__ ab)
{
  __shared__ unsigned short Ks[2][4096];    // [buf][64 kk][64 d] swizzled
  __shared__ unsigned short Vt[2][4096];    // [buf][64 d][64 kk] swizzled
  // XCD-clustered decode: 8 qt-blocks x 8 bh per XCD -> K/V set = 4MB = one L2
  int lin = blockIdx.x;                     // 512 blocks (2/CU, all co-resident)
  int xcd = lin & 7, slot = lin >> 3;       // slot in [0,64)
  int qt = slot & 7;                        // 8 q-tiles of 256 rows
  int bh = xcd + ((slot >> 3) << 3);
  int b = bh >> 4, h = bh & 15;
  const unsigned short* Q  = qbuf + (bh*2048 + qt*256)*64;
  const char* Kg = (const char*)(kbuf + bh*2048*64);      // rows n, 128B, contiguous
  const char* Vg = (const char*)(vbuf + bh*64*2048);      // rows d, 4096B stride
  char* ldsK = (char*)Ks; char* ldsV = (char*)Vt;
  int tid = threadIdx.x, lane = tid & 63, wv = tid >> 6;
  int lr = lane & 15, lg = lane >> 4;

  // staging geometry: per wave 2 rounds of 1KB; pre-swizzled global source (rule 21)
  int so[2], srow[2];
  #pragma unroll
  for (int r = 0; r < 2; ++r){
    int o = r*4096 + wv*1024 + lane*16;
    srow[r] = o >> 7;
    so[r] = (o & 127) ^ ((srow[r] & 7) << 4);
  }

  // loop-invariant swizzled read bases:
  // byte(row=ni*16+lr, inrow=ks*64+lg*16) = ni*2048 + lr*128 + ((lg*16)^((lr&3)<<4)) + ((ks*64)^((lr&4)<<4))
  int lb  = lr*128 + ((lg*16) ^ ((lr&3)<<4));
  int ksA = (lr & 4) << 4;                  // ks=0 term
  const char* kv0 = ldsK + lb + ksA;
  const char* kv1 = ldsK + lb + (64 - ksA); // ks=1 term
  const char* vv0 = ldsV + lb + ksA;
  const char* vv1 = ldsV + lb + (64 - ksA);

  short8v qf[4][2];   // 64 q-rows per wave: rows wv*64 + mi*16 + lr within the 256-row tile
  #pragma unroll
  for (int mi = 0; mi < 4; ++mi)
    #pragma unroll
    for (int ks = 0; ks < 2; ++ks)
      qf[mi][ks] = *(const short8v*)&Q[(wv*64 + mi*16 + lr)*64 + ks*32 + lg*8];

  f32x4 oacc[4][4];
  #pragma unroll
  for (int mi = 0; mi < 4; ++mi)
    #pragma unroll
    for (int nf = 0; nf < 4; ++nf) oacc[mi][nf] = (f32x4){0.f,0.f,0.f,0.f};
  float den[4] = {0.f, 0.f, 0.f, 0.f};   // per-lane partial for q = wv*64 + mi*16 + lr

  // prologue: stage tile 0 into buf 0
  #pragma unroll
  for (int r = 0; r < 2; ++r){
    gll16(Kg + srow[r]*128  + so[r], ldsK + r*4096 + wv*1024);
    gll16(Vg + srow[r]*4096 + so[r], ldsV + r*4096 + wv*1024);
  }
  __syncthreads();

  #pragma unroll 1
  for (int tt = 0; tt < 16; ++tt){
    int t0 = tt << 1;
    TILE_BODY(0, t0+1, 1, 1)
    TILE_BODY(1, t0+2, 0, (tt < 15))
  }

  // epilogue: complete den (sum across lg copies), redistribute to C-layout rows, store
  #pragma unroll
  for (int mi = 0; mi < 4; ++mi){
    float d = den[mi];
    d += __shfl_xor(d, 16, 64);
    d += __shfl_xor(d, 32, 64);
    den[mi] = d;                 // lane (lr,lg) now holds full den for q=wv*64+mi*16+lr
  }
  #pragma unroll
  for (int mi = 0; mi < 4; ++mi){
    #pragma unroll
    for (int j = 0; j < 4; ++j){
      float dd = __shfl(den[mi], lg*4 + j, 64);   // den for q-row lg*4+j (lane lr==lg*4+j)
      int n = qt*256 + wv*64 + mi*16 + lg*4 + j;
      float mv = mWin[b*2048 + n];
      float g = 1.0f / (dd * (mv * cnt[b] + 1e-6f));
      #pragma unroll
      for (int nf = 0; nf < 4; ++nf)
        ab[(b*2048 + n)*1024 + h*64 + nf*16 + lr] = f2b(oacc[mi][nf][j] * g);
    }
  }
}

// ---------------- proj GEMM: ab[8192x1024] @ wproj[1024x1024]^T + bias -> fp32 out ----------------
__global__ __launch_bounds__(256,2) void proj_gemm(
    const unsigned short* __restrict__ abuf,
    const unsigned short* __restrict__ wb,
    const float* __restrict__ pb,
    float* __restrict__ out)
{
  __shared__ unsigned short As[128*64];
  __shared__ unsigned short Bs[128*64];
  int lin = blockIdx.x;                      // 512 blocks
  // XCD owns 8 tM rows (A-panel L2-resident), iterates tN:
  int xcd = lin & 7, slot = lin >> 3;        // slot in [0,64)
  int tM = xcd*8 + (slot & 7);               // [0,64)
  int tN = slot >> 3;                        // [0,8)
  int tid = threadIdx.x, lane = tid & 63, wv = tid >> 6;
  int lr = lane & 15, lg = lane >> 4;

  const unsigned short* ga[4]; const unsigned short* gbp[4];
  char* lA[4]; char* lB[4];
  #pragma unroll
  for (int c = 0; c < 4; ++c){
    int o = c*4096 + wv*1024 + lane*16;
    int row = o >> 7, cole = (o & 127) >> 1;
    ga[c]  = abuf + (tM*128 + row)*1024 + cole;
    gbp[c] = wb   + (tN*128 + row)*1024 + cole;
    lA[c] = (char*)As + c*4096 + wv*1024;
    lB[c] = (char*)Bs + c*4096 + wv*1024;
  }

  f32x4 acc[4][4];
  #pragma unroll
  for (int i = 0; i < 4; ++i)
    #pragma unroll
    for (int j = 0; j < 4; ++j) acc[i][j] = (f32x4){0.f,0.f,0.f,0.f};

  int wr = (wv >> 1) * 64, wc = (wv & 1) * 64;

  for (int it = 0; it < 16; ++it){
    #pragma unroll
    for (int c = 0; c < 4; ++c){
      gll16(ga[c]  + it*64, lA[c]);
      gll16(gbp[c] + it*64, lB[c]);
    }
    __syncthreads();
    short8v af[4][2], bf[4][2];
    #pragma unroll
    for (int mi = 0; mi < 4; ++mi)
      #pragma unroll
      for (int ks = 0; ks < 2; ++ks)
        af[mi][ks] = *(const short8v*)&As[(wr + mi*16 + lr)*64 + ks*32 + lg*8];
    #pragma unroll
    for (int ni = 0; ni < 4; ++ni)
      #pragma unroll
      for (int ks = 0; ks < 2; ++ks)
        bf[ni][ks] = *(const short8v*)&Bs[(wc + ni*16 + lr)*64 + ks*32 + lg*8];
    #pragma unroll
    for (int mi = 0; mi < 4; ++mi)
      #pragma unroll
      for (int ni = 0; ni < 4; ++ni)
        #pragma unroll
        for (int ks = 0; ks < 2; ++ks)
          acc[mi][ni] = MFMA(af[mi][ks], bf[ni][ks], acc[mi][ni]);
    __syncthreads();
  }

  #pragma unroll
  for (int mi = 0; mi < 4; ++mi){
    #pragma unroll
    for (int j = 0; j < 4; ++j){
      int m = tM*128 + wr + mi*16 + lg*4 + j;
      #pragma unroll
      for (int ni = 0; ni < 4; ++ni){
        int col = tN*128 + wc + ni*16 + lr;
        out[m*1024 + col] = acc[mi][ni][j] + pb[col];
      }
    }
  }
}

extern "C" void kernel_launch(void* const* d_in, const int* in_sizes, int n_in,
                              void* d_out, int out_size, void* d_ws, size_t ws_size,
                              hipStream_t stream) {
  const float* x      = (const float*)d_in[0];
  const float* mWin   = (const float*)d_in[1];
  const float* qkv_w  = (const float*)d_in[2];
  const float* proj_w = (const float*)d_in[3];
  const float* proj_b = (const float*)d_in[4];
  float* out = (float*)d_out;
  char* ws = (char*)d_ws;

  // workspace layout (bytes); ab aliases xb (xb dead after qkv_gemm)
  unsigned short* xb     = (unsigned short*)(ws);                 // 16 MB
  unsigned short* ab     = (unsigned short*)(ws);                 // alias
  unsigned short* wqkvb  = (unsigned short*)(ws + 16777216);      //  6 MB
  unsigned short* wprojb = (unsigned short*)(ws + 23068672);      //  2 MB
  unsigned short* qb     = (unsigned short*)(ws + 25165824);      // 16 MB
  unsigned short* kb     = (unsigned short*)(ws + 41943040);      // 16 MB
  unsigned short* vb     = (unsigned short*)(ws + 58720256);      // 16 MB (transposed)
  float* cnt             = (float*)(ws + 75497472);               // 16 B

  prep_k<<<3076, 256, 0, stream>>>(x, qkv_w, proj_w, mWin, xb, wqkvb, wprojb, cnt);
  qkv_gemm<<<1536, 256, 0, stream>>>(xb, wqkvb, mWin, qb, kb, vb);
  attn_k<<<512, 256, 0, stream>>>(qb, kb, vb, mWin, cnt, ab);
  proj_gemm<<<512, 256, 0, stream>>>(ab, wprojb, proj_b, out);
}